// Round 2
// baseline (425.874 us; speedup 1.0000x reference)
//
#include <hip/hip_runtime.h>
#include <hip/hip_bf16.h>

// Problem constants: B,N,M,HID,NH = 16,512,1024,512,8; HS=64
#define BB 16
#define NN 512
#define MM 1024
#define HIDD 512
#define NHH 8

typedef unsigned short ushort_t;
typedef __attribute__((ext_vector_type(8))) short short8;      // 8 bf16
typedef __attribute__((ext_vector_type(8))) _Float16 half8;    // 8 fp16
typedef __attribute__((ext_vector_type(4))) _Float16 half4;
typedef __attribute__((ext_vector_type(4))) float f32x4;

__device__ __forceinline__ ushort_t f2bf(float x) {   // RNE fp32->bf16
    unsigned u = __float_as_uint(x);
    u += 0x7fff + ((u >> 16) & 1);
    return (ushort_t)(u >> 16);
}

// async global->LDS, 16B per lane (GEMM staging; layout contiguous per wave)
#define GLD16(g, l) __builtin_amdgcn_global_load_lds(                      \
    (const __attribute__((address_space(1))) void*)(g),                    \
    (__attribute__((address_space(3))) void*)(l), 16, 0, 0)

// XCD-aware swizzle: consecutive linear block ids land on XCD id%8.
__device__ __forceinline__ void xcd_swizzle(int& colb, int& rowb) {
    int id = blockIdx.x + blockIdx.y * gridDim.x;
    int C = gridDim.x;
    int xcd = id & 7;
    int slot = id >> 3;
    int rows_per = gridDim.y >> 3;
    colb = slot % C;
    rowb = xcd * rows_per + slot / C;
}

// ---------------------------------------------------------------------------
// bf16 MFMA GEMM, tile 128x128, BK=32, 4 waves (2x2 of 64x64). Double-buffered.
// ---------------------------------------------------------------------------
__global__ __launch_bounds__(256)
void gemm_bf(const ushort_t* __restrict__ A, const ushort_t* __restrict__ W,
             const float* __restrict__ bias, float* __restrict__ C,
             ushort_t* __restrict__ Cb, _Float16* __restrict__ Ch,
             int K, int Cout, int relu) {
    __shared__ __align__(16) ushort_t smem[2][8192];
    const int tid = threadIdx.x;
    const int lane = tid & 63;
    const int wid = tid >> 6;
    const int wm = wid >> 1, wn = wid & 1;
    int colb, rowb;
    xcd_swizzle(colb, rowb);
    const long row0 = (long)rowb * 128;
    const long col0 = (long)colb * 128;

    const int sr = lane >> 2;
    const int skq = lane & 3;
    const ushort_t* Ag = A + (row0 + wid * 32 + sr) * (long)K + skq * 8;
    const ushort_t* Wg = W + (col0 + wid * 32 + sr) * (long)K + skq * 8;
    const int sa0 = (wid * 32) * 32, sa1 = (wid * 32 + 16) * 32;

    f32x4 acc[4][4] = {};
    const int lr = lane & 15;
    const int kg = lane >> 4;

    GLD16(Ag, &smem[0][sa0]);
    GLD16(Ag + 16 * (long)K, &smem[0][sa1]);
    GLD16(Wg, &smem[0][4096 + sa0]);
    GLD16(Wg + 16 * (long)K, &smem[0][4096 + sa1]);

    int pb = 0;
    for (int k0 = 0; k0 < K; k0 += 32, pb ^= 1) {
        __syncthreads();
        int kn = k0 + 32;
        if (kn < K) {
            GLD16(Ag + kn, &smem[pb ^ 1][sa0]);
            GLD16(Ag + 16 * (long)K + kn, &smem[pb ^ 1][sa1]);
            GLD16(Wg + kn, &smem[pb ^ 1][4096 + sa0]);
            GLD16(Wg + 16 * (long)K + kn, &smem[pb ^ 1][4096 + sa1]);
        }
        const ushort_t* Ab = smem[pb];
        const ushort_t* Wb = smem[pb] + 4096;
        short8 af[4], bfr[4];
#pragma unroll
        for (int i = 0; i < 4; i++)
            af[i] = *(const short8*)&Ab[(wm * 64 + i * 16 + lr) * 32 + kg * 8];
#pragma unroll
        for (int j = 0; j < 4; j++)
            bfr[j] = *(const short8*)&Wb[(wn * 64 + j * 16 + lr) * 32 + kg * 8];
#pragma unroll
        for (int i = 0; i < 4; i++)
#pragma unroll
            for (int j = 0; j < 4; j++)
                acc[i][j] = __builtin_amdgcn_mfma_f32_16x16x32_bf16(
                    af[i], bfr[j], acc[i][j], 0, 0, 0);
    }

#pragma unroll
    for (int i = 0; i < 4; i++) {
#pragma unroll
        for (int j = 0; j < 4; j++) {
            long row = row0 + wm * 64 + i * 16 + kg * 4;
            long col = col0 + wn * 64 + j * 16 + lr;
            float bv = bias ? bias[col] : 0.f;
#pragma unroll
            for (int r = 0; r < 4; r++) {
                float x = acc[i][j][r] + bv;
                if (relu) x = fmaxf(x, 0.f);
                size_t idx = (row + r) * (size_t)Cout + col;
                if (Ch)      Ch[idx] = (_Float16)x;
                else if (Cb) Cb[idx] = f2bf(x);
                else         C[idx] = x;
            }
        }
    }
}

// ---------------------------------------------------------------------------
// bf16 MFMA GEMM, tile 128x64, BK=32, 4 waves, each 32x64. Double-buffered.
// ---------------------------------------------------------------------------
__global__ __launch_bounds__(256)
void gemm_bf64(const ushort_t* __restrict__ A, const ushort_t* __restrict__ W,
               const float* __restrict__ bias, float* __restrict__ C,
               ushort_t* __restrict__ Cb, _Float16* __restrict__ Ch,
               int K, int Cout, int relu) {
    __shared__ __align__(16) ushort_t smem[2][6144];
    const int tid = threadIdx.x;
    const int lane = tid & 63;
    const int w = tid >> 6;
    int colb, rowb;
    xcd_swizzle(colb, rowb);
    const long row0 = (long)rowb * 128;
    const long col0 = (long)colb * 64;

    const int sr = lane >> 2;
    const int skq = lane & 3;
    const ushort_t* Ag = A + (row0 + w * 32 + sr) * (long)K + skq * 8;
    const ushort_t* Wg = W + (col0 + w * 16 + sr) * (long)K + skq * 8;
    const int sa0 = (w * 32) * 32, sa1 = (w * 32 + 16) * 32;
    const int sw0 = 4096 + (w * 16) * 32;

    f32x4 acc[2][4] = {};
    const int lr = lane & 15;
    const int kg = lane >> 4;

    GLD16(Ag, &smem[0][sa0]);
    GLD16(Ag + 16 * (long)K, &smem[0][sa1]);
    GLD16(Wg, &smem[0][sw0]);

    int pb = 0;
    for (int k0 = 0; k0 < K; k0 += 32, pb ^= 1) {
        __syncthreads();
        int kn = k0 + 32;
        if (kn < K) {
            GLD16(Ag + kn, &smem[pb ^ 1][sa0]);
            GLD16(Ag + 16 * (long)K + kn, &smem[pb ^ 1][sa1]);
            GLD16(Wg + kn, &smem[pb ^ 1][sw0]);
        }
        const ushort_t* Ab = smem[pb];
        const ushort_t* Wb = smem[pb] + 4096;
        short8 af[2], bfr[4];
#pragma unroll
        for (int i = 0; i < 2; i++)
            af[i] = *(const short8*)&Ab[(w * 32 + i * 16 + lr) * 32 + kg * 8];
#pragma unroll
        for (int j = 0; j < 4; j++)
            bfr[j] = *(const short8*)&Wb[(j * 16 + lr) * 32 + kg * 8];
#pragma unroll
        for (int i = 0; i < 2; i++)
#pragma unroll
            for (int j = 0; j < 4; j++)
                acc[i][j] = __builtin_amdgcn_mfma_f32_16x16x32_bf16(
                    af[i], bfr[j], acc[i][j], 0, 0, 0);
    }

#pragma unroll
    for (int i = 0; i < 2; i++) {
#pragma unroll
        for (int j = 0; j < 4; j++) {
            long row = row0 + w * 32 + i * 16 + kg * 4;
            long col = col0 + j * 16 + lr;
            float bv = bias ? bias[col] : 0.f;
#pragma unroll
            for (int r = 0; r < 4; r++) {
                float x = acc[i][j][r] + bv;
                if (relu) x = fmaxf(x, 0.f);
                size_t idx = (row + r) * (size_t)Cout + col;
                if (Ch)      Ch[idx] = (_Float16)x;
                else if (Cb) Cb[idx] = f2bf(x);
                else         C[idx] = x;
            }
        }
    }
}

// ---------------------------------------------------------------------------
// gemm_bf64_sk: split-K=2 variant for h @ w2.T (A stride lda, K-slice per z).
// z = blockIdx.z selects k-slice and output buffer (C0 / C1); LN sums them.
// Doubles resident blocks (4/CU) for the K=2048 down-proj.
// ---------------------------------------------------------------------------
__global__ __launch_bounds__(256)
void gemm_bf64_sk(const ushort_t* __restrict__ A, const ushort_t* __restrict__ W,
                  int lda, int Kslice, float* __restrict__ C0,
                  float* __restrict__ C1, int Cout) {
    __shared__ __align__(16) ushort_t smem[2][6144];
    const int tid = threadIdx.x;
    const int lane = tid & 63;
    const int w = tid >> 6;
    int colb, rowb;
    xcd_swizzle(colb, rowb);
    const long row0 = (long)rowb * 128;
    const long col0 = (long)colb * 64;
    const long koff = (long)blockIdx.z * Kslice;
    float* __restrict__ C = blockIdx.z ? C1 : C0;

    const int sr = lane >> 2;
    const int skq = lane & 3;
    const ushort_t* Ag = A + (row0 + w * 32 + sr) * (long)lda + koff + skq * 8;
    const ushort_t* Wg = W + (col0 + w * 16 + sr) * (long)lda + koff + skq * 8;
    const int sa0 = (w * 32) * 32, sa1 = (w * 32 + 16) * 32;
    const int sw0 = 4096 + (w * 16) * 32;

    f32x4 acc[2][4] = {};
    const int lr = lane & 15;
    const int kg = lane >> 4;

    GLD16(Ag, &smem[0][sa0]);
    GLD16(Ag + 16 * (long)lda, &smem[0][sa1]);
    GLD16(Wg, &smem[0][sw0]);

    int pb = 0;
    for (int k0 = 0; k0 < Kslice; k0 += 32, pb ^= 1) {
        __syncthreads();
        int kn = k0 + 32;
        if (kn < Kslice) {
            GLD16(Ag + kn, &smem[pb ^ 1][sa0]);
            GLD16(Ag + 16 * (long)lda + kn, &smem[pb ^ 1][sa1]);
            GLD16(Wg + kn, &smem[pb ^ 1][sw0]);
        }
        const ushort_t* Ab = smem[pb];
        const ushort_t* Wb = smem[pb] + 4096;
        short8 af[2], bfr[4];
#pragma unroll
        for (int i = 0; i < 2; i++)
            af[i] = *(const short8*)&Ab[(w * 32 + i * 16 + lr) * 32 + kg * 8];
#pragma unroll
        for (int j = 0; j < 4; j++)
            bfr[j] = *(const short8*)&Wb[(j * 16 + lr) * 32 + kg * 8];
#pragma unroll
        for (int i = 0; i < 2; i++)
#pragma unroll
            for (int j = 0; j < 4; j++)
                acc[i][j] = __builtin_amdgcn_mfma_f32_16x16x32_bf16(
                    af[i], bfr[j], acc[i][j], 0, 0, 0);
    }

#pragma unroll
    for (int i = 0; i < 2; i++)
#pragma unroll
        for (int j = 0; j < 4; j++) {
            long row = row0 + w * 32 + i * 16 + kg * 4;
            long col = col0 + j * 16 + lr;
#pragma unroll
            for (int r = 0; r < 4; r++)
                C[(row + r) * (size_t)Cout + col] = acc[i][j][r];
        }
}

// ---------------------------------------------------------------------------
// gemm_q_rot: 128x64-tile GEMM (Cout=512, K=512), col-block = one head.
// Double-buffered; epilogue Cs overlays staging LDS; rotates -> Qrot f16.
// ---------------------------------------------------------------------------
__global__ __launch_bounds__(256)
void gemm_q_rot(const ushort_t* __restrict__ A, const ushort_t* __restrict__ W,
                const float* __restrict__ bias,
                const float* __restrict__ sn, const float* __restrict__ cs,
                _Float16* __restrict__ Qrot) {
    __shared__ __align__(16) ushort_t smem[2][6144];
    _Float16* Cs = (_Float16*)smem;
    const int K = 512;
    const int tid = threadIdx.x;
    const int lane = tid & 63;
    const int w = tid >> 6;
    int colb, rowb;
    xcd_swizzle(colb, rowb);
    const long row0 = (long)rowb * 128;
    const int h = colb;
    const long col0 = (long)h * 64;

    const int sr = lane >> 2;
    const int skq = lane & 3;
    const ushort_t* Ag = A + (row0 + w * 32 + sr) * (long)K + skq * 8;
    const ushort_t* Wg = W + (col0 + w * 16 + sr) * (long)K + skq * 8;
    const int sa0 = (w * 32) * 32, sa1 = (w * 32 + 16) * 32;
    const int sw0 = 4096 + (w * 16) * 32;

    f32x4 acc[2][4] = {};
    const int lr = lane & 15;
    const int kg = lane >> 4;

    GLD16(Ag, &smem[0][sa0]);
    GLD16(Ag + 16 * (long)K, &smem[0][sa1]);
    GLD16(Wg, &smem[0][sw0]);

    int pb = 0;
    for (int k0 = 0; k0 < K; k0 += 32, pb ^= 1) {
        __syncthreads();
        int kn = k0 + 32;
        if (kn < K) {
            GLD16(Ag + kn, &smem[pb ^ 1][sa0]);
            GLD16(Ag + 16 * (long)K + kn, &smem[pb ^ 1][sa1]);
            GLD16(Wg + kn, &smem[pb ^ 1][sw0]);
        }
        const ushort_t* Ab = smem[pb];
        const ushort_t* Wb = smem[pb] + 4096;
        short8 af[2], bfr[4];
#pragma unroll
        for (int i = 0; i < 2; i++)
            af[i] = *(const short8*)&Ab[(w * 32 + i * 16 + lr) * 32 + kg * 8];
#pragma unroll
        for (int j = 0; j < 4; j++)
            bfr[j] = *(const short8*)&Wb[(j * 16 + lr) * 32 + kg * 8];
#pragma unroll
        for (int i = 0; i < 2; i++)
#pragma unroll
            for (int j = 0; j < 4; j++)
                acc[i][j] = __builtin_amdgcn_mfma_f32_16x16x32_bf16(
                    af[i], bfr[j], acc[i][j], 0, 0, 0);
    }

    __syncthreads();
#pragma unroll
    for (int i = 0; i < 2; i++)
#pragma unroll
        for (int j = 0; j < 4; j++) {
            int row = w * 32 + i * 16 + kg * 4;
            int col = j * 16 + lr;
            float bv = bias[col0 + col];
#pragma unroll
            for (int r = 0; r < 4; r++)
                Cs[(row + r) * 76 + col] = (_Float16)(acc[i][j][r] + bv);
        }
    __syncthreads();
    for (int idx = tid; idx < 4096; idx += 256) {
        int rr = idx >> 5, j = idx & 31;
        size_t srow = (size_t)row0 + rr;
        float x0 = (float)Cs[rr * 76 + 2 * j], x1 = (float)Cs[rr * 76 + 2 * j + 1];
        float s = sn[srow * 32 + j], c = cs[srow * 32 + j];
        Qrot[srow * 512 + h * 64 + j]      = (_Float16)(x0 * c - x1 * s);
        Qrot[srow * 512 + h * 64 + 32 + j] = (_Float16)(x1 * c + x0 * s);
    }
}

// ---------------------------------------------------------------------------
// gemm_kv: 128x128-tile GEMM (Cout=1024, K=512), col-block = one head's k|v.
// Double-buffered; epilogue: rotate k -> Krot, transpose v -> Vth.
// ---------------------------------------------------------------------------
__global__ __launch_bounds__(256)
void gemm_kv(const ushort_t* __restrict__ A, const ushort_t* __restrict__ W,
             const float* __restrict__ bias,
             const float* __restrict__ sn, const float* __restrict__ cs,
             _Float16* __restrict__ Krot, _Float16* __restrict__ Vth) {
    __shared__ __align__(16) ushort_t smem[2][8192];
    _Float16* Cs = (_Float16*)smem;
    const int K = 512;
    const int tid = threadIdx.x;
    const int lane = tid & 63;
    const int wid = tid >> 6;
    const int wm = wid >> 1, wn = wid & 1;
    int colb, rowb;
    xcd_swizzle(colb, rowb);
    const long row0 = (long)rowb * 128;
    const int h = colb;
    const long col0 = (long)h * 128;

    const int sr = lane >> 2;
    const int skq = lane & 3;
    const ushort_t* Ag = A + (row0 + wid * 32 + sr) * (long)K + skq * 8;
    const ushort_t* Wg = W + (col0 + wid * 32 + sr) * (long)K + skq * 8;
    const int sa0 = (wid * 32) * 32, sa1 = (wid * 32 + 16) * 32;

    f32x4 acc[4][4] = {};
    const int lr = lane & 15;
    const int kg = lane >> 4;

    GLD16(Ag, &smem[0][sa0]);
    GLD16(Ag + 16 * (long)K, &smem[0][sa1]);
    GLD16(Wg, &smem[0][4096 + sa0]);
    GLD16(Wg + 16 * (long)K, &smem[0][4096 + sa1]);

    int pb = 0;
    for (int k0 = 0; k0 < K; k0 += 32, pb ^= 1) {
        __syncthreads();
        int kn = k0 + 32;
        if (kn < K) {
            GLD16(Ag + kn, &smem[pb ^ 1][sa0]);
            GLD16(Ag + 16 * (long)K + kn, &smem[pb ^ 1][sa1]);
            GLD16(Wg + kn, &smem[pb ^ 1][4096 + sa0]);
            GLD16(Wg + 16 * (long)K + kn, &smem[pb ^ 1][4096 + sa1]);
        }
        const ushort_t* Ab = smem[pb];
        const ushort_t* Wb = smem[pb] + 4096;
        short8 af[4], bfr[4];
#pragma unroll
        for (int i = 0; i < 4; i++)
            af[i] = *(const short8*)&Ab[(wm * 64 + i * 16 + lr) * 32 + kg * 8];
#pragma unroll
        for (int j = 0; j < 4; j++)
            bfr[j] = *(const short8*)&Wb[(wn * 64 + j * 16 + lr) * 32 + kg * 8];
#pragma unroll
        for (int i = 0; i < 4; i++)
#pragma unroll
            for (int j = 0; j < 4; j++)
                acc[i][j] = __builtin_amdgcn_mfma_f32_16x16x32_bf16(
                    af[i], bfr[j], acc[i][j], 0, 0, 0);
    }

    const int b_ = (int)(row0 >> 10);
    const int m0_ = (int)(row0 & 1023);
#pragma unroll
    for (int half = 0; half < 2; half++) {
        __syncthreads();
        if (wn == half) {
#pragma unroll
            for (int i = 0; i < 4; i++)
#pragma unroll
                for (int j = 0; j < 4; j++) {
                    int row = wm * 64 + i * 16 + kg * 4;
                    int col = j * 16 + lr;
                    float bv = bias[col0 + half * 64 + col];
#pragma unroll
                    for (int r = 0; r < 4; r++)
                        Cs[(row + r) * 76 + col] = (_Float16)(acc[i][j][r] + bv);
                }
        }
        __syncthreads();
        if (half == 0) {
            for (int idx = tid; idx < 4096; idx += 256) {
                int rr = idx >> 5, j = idx & 31;
                size_t srow = (size_t)row0 + rr;
                float x0 = (float)Cs[rr * 76 + 2 * j], x1 = (float)Cs[rr * 76 + 2 * j + 1];
                float s = sn[srow * 32 + j], c = cs[srow * 32 + j];
                Krot[srow * 512 + h * 64 + j]      = (_Float16)(x0 * c - x1 * s);
                Krot[srow * 512 + h * 64 + 32 + j] = (_Float16)(x1 * c + x0 * s);
            }
        } else {
            for (int idx = tid; idx < 1024; idx += 256) {
                int d = idx >> 4, c = idx & 15;
                half8 v;
#pragma unroll
                for (int k = 0; k < 8; k++) v[k] = Cs[(c * 8 + k) * 76 + d];
                *(half8*)(Vth + (((size_t)(b_ * NHH + h)) * 64 + d) * MM
                          + m0_ + c * 8) = v;
            }
        }
    }
}

// ---------------------------------------------------------------------------
// One-shot fp32->bf16 convert of tgt, mem, and all 7 weight mats.
// ---------------------------------------------------------------------------
__global__ __launch_bounds__(256)
void cvt_all(const float* __restrict__ tgt, const float* __restrict__ mem,
             const float* __restrict__ w0, const float* __restrict__ w1,
             const float* __restrict__ w2, const float* __restrict__ w3,
             const float* __restrict__ w4, const float* __restrict__ w5,
             const float* __restrict__ w6,
             ushort_t* __restrict__ Abf, ushort_t* __restrict__ membf,
             ushort_t* __restrict__ Wbf) {
    int blk = blockIdx.x;
    const float* src;
    ushort_t* dst;
    size_t off;
    if (blk < 4096)       { src = tgt; dst = Abf;   off = (size_t)blk * 1024; }
    else if (blk < 12288) { src = mem; dst = membf; off = (size_t)(blk - 4096) * 1024; }
    else {
        int wb = blk - 12288;
        dst = Wbf + (size_t)wb * 1024;
        if (wb < 768)       { src = w0; off = (size_t)wb * 1024; }
        else if (wb < 1024) { src = w1; off = (size_t)(wb - 768) * 1024; }
        else if (wb < 1280) { src = w2; off = (size_t)(wb - 1024) * 1024; }
        else if (wb < 1792) { src = w3; off = (size_t)(wb - 1280) * 1024; }
        else if (wb < 2048) { src = w4; off = (size_t)(wb - 1792) * 1024; }
        else if (wb < 3072) { src = w5; off = (size_t)(wb - 2048) * 1024; }
        else                { src = w6; off = (size_t)(wb - 3072) * 1024; }
        float4 v = *(const float4*)(src + off + threadIdx.x * 4);
        ushort4 o;
        o.x = f2bf(v.x); o.y = f2bf(v.y); o.z = f2bf(v.z); o.w = f2bf(v.w);
        *(ushort4*)(dst + threadIdx.x * 4) = o;
        return;
    }
    float4 v = *(const float4*)(src + off + threadIdx.x * 4);
    ushort4 o;
    o.x = f2bf(v.x); o.y = f2bf(v.y); o.z = f2bf(v.z); o.w = f2bf(v.w);
    *(ushort4*)(dst + off + threadIdx.x * 4) = o;
}

// ---------------------------------------------------------------------------
// prep_vt: transpose 64-wide V slice per head (self-attention path).
// ---------------------------------------------------------------------------
__global__ __launch_bounds__(256)
void prep_vt(const _Float16* __restrict__ src, int L, int stride,
             int hmul, int hadd, _Float16* __restrict__ Vt) {
    const int b = blockIdx.z, h = blockIdx.y, m0 = blockIdx.x * 64;
    const int tid = threadIdx.x;
    __shared__ _Float16 vt[64][72];
    for (int idx = tid; idx < 512; idx += 256) {
        int m = idx >> 3, c = idx & 7;
        half8 v = *(const half8*)(src + ((size_t)(b * L + m0 + m)) * stride
                                  + h * hmul + hadd + c * 8);
#pragma unroll
        for (int k = 0; k < 8; k++) vt[c * 8 + k][m] = v[k];
    }
    __syncthreads();
    for (int idx = tid; idx < 512; idx += 256) {
        int d = idx >> 3, c = idx & 7;
        *(half8*)(Vt + (((size_t)(b * NHH + h)) * 64 + d) * L + m0 + c * 8)
            = *(const half8*)&vt[d][c * 8];
    }
}

// ---------------------------------------------------------------------------
// Flash MFMA attention v9: KVBLK=128 per barrier, ONE unified softmax per
// 128 keys. vs v8: (1) one barrier + one fmax-reduce + one mrun/corr update
// + one ls-reduce per 128 keys (was per 64) -> halves barrier count and
// softmax serial chains; (2) P LDS buffer time-shared between sub-tiles
// (ap0 read before P1 writes; same-wave LDS ops are ordered); (3) causal
// sub-tile skip (do1) avoids wasted work for low waves in the last iter.
// LDS = Ks 2x16K + Vs 2x16K + Ps 16K = 80 KB -> exactly 2 blocks/CU
// (grid-bound at 2 anyway). Defer-max, exp2-form, setprio kept from v8.
// ---------------------------------------------------------------------------
__global__ __launch_bounds__(512, 4)
void attn9(const _Float16* __restrict__ Q, int qstride, int qmul, int qadd,
           const _Float16* __restrict__ K, int kstride, int kmul, int kadd,
           const _Float16* __restrict__ Vt, int LV, int Lrows,
           ushort_t* __restrict__ out, int kvlen, int causal) {
    const int g = blockIdx.x;
    const int bh = (g & 7) * 16 + ((g >> 3) & 15);
    const int qb = g >> 7;
    const int b = bh >> 3, h = bh & 7;
    const int n0 = qb * 128;
    const int tid = threadIdx.x, lane = tid & 63, w = tid >> 6;
    const int quad = lane >> 4, l16 = lane & 15;
    const int qw = n0 + w * 16;                     // 16 q rows per wave

    __shared__ _Float16 Ks[2][128 * 64];            // [key][d]
    __shared__ _Float16 Vs[2][64 * 128];            // [d][key]
    __shared__ _Float16 Ps[8][16 * 64];
    _Float16* Pw = Ps[w];

    half8 bq[2];
#pragma unroll
    for (int c = 0; c < 2; c++)
        bq[c] = *(const half8*)(Q + ((size_t)(b * NN + qw + l16)) * qstride
                                + h * qmul + qadd + c * 32 + quad * 8);

    f32x4 acc[4] = {};
    float mrun = -3e38f, lrun = 0.f;

    const int srow = tid >> 3;                      // 0..63
    const int scol = tid & 7;                       // chunk index 0..7
    const int ksw = (scol ^ (srow & 7)) * 8;        // K-row swizzled chunk
    const int vsw = (scol ^ (srow & 7)) * 8;        // V chunk scol; scol+8 -> +64

    const int limit = causal ? (n0 + 128) : kvlen;
    const int nit = (limit + 127) >> 7;

    const size_t kbase = ((size_t)(b * Lrows)) * kstride + h * kmul + kadd;
    const size_t vbase = (((size_t)(b * NHH + h)) * 64 + srow) * (size_t)LV;

    // prologue: iter 0 -> buf0; issue iter-1 loads into regs
    half8 kr0 = *(const half8*)(K + kbase + (size_t)srow * kstride + scol * 8);
    half8 kr1 = *(const half8*)(K + kbase + (size_t)(64 + srow) * kstride + scol * 8);
    half8 vr0 = *(const half8*)(Vt + vbase + scol * 8);
    half8 vr1 = *(const half8*)(Vt + vbase + 64 + scol * 8);
    *(half8*)&Ks[0][srow * 64 + ksw] = kr0;
    *(half8*)&Ks[0][(64 + srow) * 64 + ksw] = kr1;
    *(half8*)&Vs[0][srow * 128 + vsw] = vr0;
    *(half8*)&Vs[0][srow * 128 + vsw + 64] = vr1;
    if (nit > 1) {
        kr0 = *(const half8*)(K + kbase + (size_t)(128 + srow) * kstride + scol * 8);
        kr1 = *(const half8*)(K + kbase + (size_t)(192 + srow) * kstride + scol * 8);
        vr0 = *(const half8*)(Vt + vbase + 128 + scol * 8);
        vr1 = *(const half8*)(Vt + vbase + 192 + scol * 8);
    }

    const float SC = 0.125f * 1.44269504f;          // scale * log2(e)
    const int fsw = l16 & 7;                        // frag-read row swizzle
    int pb = 0;
    for (int it = 0; it < nit; it++, pb ^= 1) {
        const int key0 = it * 128;
        __syncthreads();
        if (it + 1 < nit) {
            *(half8*)&Ks[pb ^ 1][srow * 64 + ksw] = kr0;
            *(half8*)&Ks[pb ^ 1][(64 + srow) * 64 + ksw] = kr1;
            *(half8*)&Vs[pb ^ 1][srow * 128 + vsw] = vr0;
            *(half8*)&Vs[pb ^ 1][srow * 128 + vsw + 64] = vr1;
            if (it + 2 < nit) {
                const int r0 = (it + 2) * 128;
                kr0 = *(const half8*)(K + kbase + (size_t)(r0 + srow) * kstride + scol * 8);
                kr1 = *(const half8*)(K + kbase + (size_t)(r0 + 64 + srow) * kstride + scol * 8);
                vr0 = *(const half8*)(Vt + vbase + r0 + scol * 8);
                vr1 = *(const half8*)(Vt + vbase + r0 + 64 + scol * 8);
            }
        }
        if (causal && key0 > qw + 15) continue;     // wave fully masked

        const _Float16* Kb = Ks[pb];
        const _Float16* Vb = Vs[pb];
        // sub-tile 1 live for this wave?
        const int do1 = (!causal) || (key0 + 64 <= qw + 15);

        f32x4 st0[4], st1[4];
        __builtin_amdgcn_s_setprio(1);
#pragma unroll
        for (int kt = 0; kt < 4; kt++) {
            const int rk = kt * 16 + l16;
            half8 ak0 = *(const half8*)&Kb[rk * 64 + ((quad ^ fsw) * 8)];
            half8 ak1 = *(const half8*)&Kb[rk * 64 + (((quad + 4) ^ fsw) * 8)];
            f32x4 z = {};
            z = __builtin_amdgcn_mfma_f32_16x16x32_f16(ak0, bq[0], z, 0, 0, 0);
            z = __builtin_amdgcn_mfma_f32_16x16x32_f16(ak1, bq[1], z, 0, 0, 0);
            st0[kt] = z;
        }
        if (do1) {
#pragma unroll
            for (int kt = 0; kt < 4; kt++) {
                const int rk = 64 + kt * 16 + l16;
                half8 ak0 = *(const half8*)&Kb[rk * 64 + ((quad ^ fsw) * 8)];
                half8 ak1 = *(const half8*)&Kb[rk * 64 + (((quad + 4) ^ fsw) * 8)];
                f32x4 z = {};
                z = __builtin_amdgcn_mfma_f32_16x16x32_f16(ak0, bq[0], z, 0, 0, 0);
                z = __builtin_amdgcn_mfma_f32_16x16x32_f16(ak1, bq[1], z, 0, 0, 0);
                st1[kt] = z;
            }
        }
        __builtin_amdgcn_s_setprio(0);

        const int qabs = qw + l16;
        if (causal) {
            if (key0 + 64 > qw) {
#pragma unroll
                for (int kt = 0; kt < 4; kt++)
#pragma unroll
                    for (int r = 0; r < 4; r++)
                        if (key0 + kt * 16 + quad * 4 + r > qabs)
                            st0[kt][r] = -3e38f;
            }
            if (do1 && key0 + 128 > qw) {
#pragma unroll
                for (int kt = 0; kt < 4; kt++)
#pragma unroll
                    for (int r = 0; r < 4; r++)
                        if (key0 + 64 + kt * 16 + quad * 4 + r > qabs)
                            st1[kt][r] = -3e38f;
            }
        } else if (key0 + 128 > kvlen) {
            if (key0 + 64 > kvlen) {
#pragma unroll
                for (int kt = 0; kt < 4; kt++)
#pragma unroll
                    for (int r = 0; r < 4; r++)
                        if (key0 + kt * 16 + quad * 4 + r >= kvlen)
                            st0[kt][r] = -3e38f;
            }
#pragma unroll
            for (int kt = 0; kt < 4; kt++)
#pragma unroll
                for (int r = 0; r < 4; r++)
                    if (key0 + 64 + kt * 16 + quad * 4 + r >= kvlen)
                        st1[kt][r] = -3e38f;
        }

        // unified softmax over up to 128 keys
        float lm = -3e38f;
#pragma unroll
        for (int kt = 0; kt < 4; kt++)
            lm = fmaxf(lm, fmaxf(fmaxf(st0[kt][0], st0[kt][1]),
                                 fmaxf(st0[kt][2], st0[kt][3])));
        if (do1) {
#pragma unroll
            for (int kt = 0; kt < 4; kt++)
                lm = fmaxf(lm, fmaxf(fmaxf(st1[kt][0], st1[kt][1]),
                                     fmaxf(st1[kt][2], st1[kt][3])));
        }
        lm = fmaxf(lm, __shfl_xor(lm, 16));
        lm = fmaxf(lm, __shfl_xor(lm, 32));

        // defer-max: keep old running max unless some row grew by >64 raw
        // (= 8 post-scale; P bounded by e^8=2981, fits f16).
        const int keep = __all(lm - mrun <= 64.f);
        float corr = 0.f;
        if (!keep) {
            float mnew = fmaxf(mrun, lm);
            corr = exp2f((mrun - mnew) * SC);
            mrun = mnew;
        }
        const float mb = mrun * SC;
        float ls = 0.f;
        // P0 -> LDS, read A-frags ap0
#pragma unroll
        for (int kt = 0; kt < 4; kt++) {
            half4 ph;
#pragma unroll
            for (int r = 0; r < 4; r++) {
                float p = exp2f(__builtin_fmaf(st0[kt][r], SC, -mb));
                ls += p;
                ph[r] = (_Float16)p;
            }
            int jc = 2 * kt + (quad >> 1);
            *(half4*)&Pw[l16 * 64 + ((jc ^ fsw) * 8) + (quad & 1) * 4] = ph;
        }
        half8 ap0[2];
#pragma unroll
        for (int c = 0; c < 2; c++)
            ap0[c] = *(const half8*)&Pw[l16 * 64 + (((c * 4 + quad) ^ fsw) * 8)];
        // P1 reuses Pw (same-wave LDS ordering guarantees ap0 reads complete)
        half8 ap1[2];
        if (do1) {
#pragma unroll
            for (int kt = 0; kt < 4; kt++) {
                half4 ph;
#pragma unroll
                for (int r = 0; r < 4; r++) {
                    float p = exp2f(__builtin_fmaf(st1[kt][r], SC, -mb));
                    ls += p;
                    ph[r] = (_Float16)p;
                }
                int jc = 2 * kt + (quad >> 1);
                *(half4*)&Pw[l16 * 64 + ((jc ^ fsw) * 8) + (quad & 1) * 4] = ph;
            }
#pragma unroll
            for (int c = 0; c < 2; c++)
                ap1[c] = *(const half8*)&Pw[l16 * 64 + (((c * 4 + quad) ^ fsw) * 8)];
        }
        ls += __shfl_xor(ls, 16);
        ls += __shfl_xor(ls, 32);
        if (keep) {
            lrun += ls;
        } else {
            lrun = lrun * corr + ls;
            float cb0 = __shfl(corr, (lane & 48) | (quad * 4 + 0));
            float cb1 = __shfl(corr, (lane & 48) | (quad * 4 + 1));
            float cb2 = __shfl(corr, (lane & 48) | (quad * 4 + 2));
            float cb3 = __shfl(corr, (lane & 48) | (quad * 4 + 3));
#pragma unroll
            for (int dt = 0; dt < 4; dt++) {
                acc[dt][0] *= cb0; acc[dt][1] *= cb1;
                acc[dt][2] *= cb2; acc[dt][3] *= cb3;
            }
        }
        __builtin_amdgcn_s_setprio(1);
#pragma unroll
        for (int dt = 0; dt < 4; dt++) {
            const int rv = dt * 16 + l16;
            half8 bv0 = *(const half8*)&Vb[rv * 128 + ((quad ^ fsw) * 8)];
            half8 bv1 = *(const half8*)&Vb[rv * 128 + (((quad + 4) ^ fsw) * 8)];
            acc[dt] = __builtin_amdgcn_mfma_f32_16x16x32_f16(ap0[0], bv0, acc[dt], 0, 0, 0);
            acc[dt] = __builtin_amdgcn_mfma_f32_16x16x32_f16(ap0[1], bv1, acc[dt], 0, 0, 0);
        }
        if (do1) {
#pragma unroll
            for (int dt = 0; dt < 4; dt++) {
                const int rv = dt * 16 + l16;
                half8 bv0 = *(const half8*)&Vb[rv * 128 + 64 + ((quad ^ fsw) * 8)];
                half8 bv1 = *(const half8*)&Vb[rv * 128 + 64 + (((quad + 4) ^ fsw) * 8)];
                acc[dt] = __builtin_amdgcn_mfma_f32_16x16x32_f16(ap1[0], bv0, acc[dt], 0, 0, 0);
                acc[dt] = __builtin_amdgcn_mfma_f32_16x16x32_f16(ap1[1], bv1, acc[dt], 0, 0, 0);
            }
        }
        __builtin_amdgcn_s_setprio(0);
    }

    float invq = 1.f / lrun;
    float iv0 = __shfl(invq, (lane & 48) | (quad * 4 + 0));
    float iv1 = __shfl(invq, (lane & 48) | (quad * 4 + 1));
    float iv2 = __shfl(invq, (lane & 48) | (quad * 4 + 2));
    float iv3 = __shfl(invq, (lane & 48) | (quad * 4 + 3));
#pragma unroll
    for (int dt = 0; dt < 4; dt++) {
        size_t base = ((size_t)(b * NN + qw + quad * 4)) * 512
                      + h * 64 + dt * 16 + l16;
        out[base]           = f2bf(acc[dt][0] * iv0);
        out[base + 512]     = f2bf(acc[dt][1] * iv1);
        out[base + 1024]    = f2bf(acc[dt][2] * iv2);
        out[base + 1536]    = f2bf(acc[dt][3] * iv3);
    }
}

// ---------------------------------------------------------------------------
// out = LayerNorm(u + (u2?) + res)*g + beta; optional bf16 copy.
// ---------------------------------------------------------------------------
__global__ __launch_bounds__(256)
void ln_residual(const float* __restrict__ u, const float* __restrict__ u2,
                 const float* __restrict__ res,
                 const float* __restrict__ g, const float* __restrict__ be,
                 float* __restrict__ out, ushort_t* __restrict__ outbf) {
    const int row = blockIdx.x, t = threadIdx.x;
    const float* rp = res + (size_t)row * HIDD;
    const float* up = u + (size_t)row * HIDD;
    float z0 = rp[t] + up[t];
    float z1 = rp[t + 256] + up[t + 256];
    if (u2) {
        const float* up2 = u2 + (size_t)row * HIDD;
        z0 += up2[t];
        z1 += up2[t + 256];
    }
    float sm = z0 + z1, s2 = z0 * z0 + z1 * z1;
#pragma unroll
    for (int off = 1; off < 64; off <<= 1) {
        sm += __shfl_xor(sm, off, 64);
        s2 += __shfl_xor(s2, off, 64);
    }
    __shared__ float ps[4], ps2[4];
    int w = t >> 6;
    if ((t & 63) == 0) { ps[w] = sm; ps2[w] = s2; }
    __syncthreads();
    sm = ps[0] + ps[1] + ps[2] + ps[3];
    s2 = ps2[0] + ps2[1] + ps2[2] + ps2[3];
    float mu = sm * (1.f / 512.f);
    float var = s2 * (1.f / 512.f) - mu * mu;
    float rstd = rsqrtf(var + 1e-5f);
    float y0 = (z0 - mu) * rstd * g[t] + be[t];
    float y1 = (z1 - mu) * rstd * g[t + 256] + be[t + 256];
    out[(size_t)row * HIDD + t]       = y0;
    out[(size_t)row * HIDD + t + 256] = y1;
    if (outbf) {
        outbf[(size_t)row * HIDD + t]       = f2bf(y0);
        outbf[(size_t)row * HIDD + t + 256] = f2bf(y1);
    }
}

// ---------------------------------------------------------------------------
extern "C" void kernel_launch(void* const* d_in, const int* in_sizes, int n_in,
                              void* d_out, int out_size, void* d_ws, size_t ws_size,
                              hipStream_t stream) {
    const float* tgt      = (const float*)d_in[0];
    const float* mem      = (const float*)d_in[1];
    const float* pep_sin  = (const float*)d_in[2];
    const float* pep_cos  = (const float*)d_in[3];
    const float* pk_sin   = (const float*)d_in[4];
    const float* pk_cos   = (const float*)d_in[5];
    const float* mmha_w   = (const float*)d_in[8];
    const float* mmha_b   = (const float*)d_in[9];
    const float* mmha_ow  = (const float*)d_in[10];
    const float* mmha_ob  = (const float*)d_in[11];
    const float* mmha_g   = (const float*)d_in[12];
    const float* mmha_be  = (const float*)d_in[13];
    const float* mha_qw   = (const float*)d_in[14];
    const float* mha_qb   = (const float*)d_in[15];
    const float* mha_kvw  = (const float*)d_in[16];
    const float* mha_kvb  = (const float*)d_in[17];
    const float* mha_ow   = (const float*)d_in[18];
    const float* mha_ob   = (const float*)d_in[19];
    const float* mha_g    = (const float*)d_in[20];
    const float* mha_be   = (const float*)d_in[21];
    const float* ffn_w1   = (const float*)d_in[22];
    const float* ffn_w2   = (const float*)d_in[23];
    const float* ffn_g    = (const float*)d_in[24];
    const float* ffn_be   = (const float*)d_in[25];

    float* ws = (float*)d_ws;
    float* utmp  = ws;                        //  4,194,304 f32
    float* tgt12 = ws + 4194304;              //  4,194,304 f32
    _Float16* hp = (_Float16*)(ws + 8388608); // half pool (offsets in halves)
    _Float16* qkvh  = hp;                     // 12,582,912 (B*N*1536)
    _Float16* Qrot  = hp + 12582912;          //  4,194,304
    _Float16* Vth   = hp + 16777216;          //  8,388,608 (self uses half)
    _Float16* Krot  = hp + 25165824;          //  8,388,608
    ushort_t* membf = (ushort_t*)(hp + 33554432); // 8,388,608 bf16
    ushort_t* Abf   = (ushort_t*)(hp + 41943040); // 4,194,304 bf16
    ushort_t* Wbf   = (ushort_t*)(hp + 46137344); // 4,194,304 bf16 weights
    ushort_t* w_mmha = Wbf;                   //   786,432
    ushort_t* w_mmow = Wbf + 786432;          //   262,144
    ushort_t* w_qw   = Wbf + 1048576;         //   262,144
    ushort_t* w_kvw  = Wbf + 1310720;         //   524,288
    ushort_t* w_mow  = Wbf + 1835008;         //   262,144
    ushort_t* w_f1   = Wbf + 2097152;         // 1,048,576
    ushort_t* w_f2   = Wbf + 3145728;         // 1,048,576
    ushort_t* hbf = (ushort_t*)qkvh;          // ffn hidden bf16 spans qkvh+Qrot
    float* utmp2 = (float*)Krot;              // dead after cross-attn; split-K slice 1
    float* out = (float*)d_out;
    (void)in_sizes; (void)n_in; (void)out_size; (void)ws_size;

    // 0. all fp32->bf16 converts in one launch
    cvt_all<<<16384, 256, 0, stream>>>(tgt, mem, mmha_w, mmha_ow, mha_qw,
                                       mha_kvw, mha_ow, ffn_w1, ffn_w2,
                                       Abf, membf, Wbf);
    // 1. qkv = tgt @ mmha_w.T + b  (8192x512x1536, f16 out)
    gemm_bf<<<dim3(12, 64), 256, 0, stream>>>(Abf, w_mmha, mmha_b, nullptr, nullptr, qkvh, 512, 1536, 0);
    // 2. self-attention (causal), KVBLK=128 attn9
    prep_vt<<<dim3(8, NHH, BB), 256, 0, stream>>>(qkvh, NN, 1536, 192, 128, Vth);
    attn9<<<512, 512, 0, stream>>>(qkvh, 1536, 192, 0, qkvh, 1536, 192, 64,
                                   Vth, NN, NN, Abf, 0, 1);
    // 3. tgt1 = LN(x @ ow.T + ob + tgt)
    gemm_bf64<<<dim3(8, 64), 256, 0, stream>>>(Abf, w_mmow, mmha_ob, utmp, nullptr, nullptr, 512, 512, 0);
    ln_residual<<<8192, 256, 0, stream>>>(utmp, nullptr, tgt, mmha_g, mmha_be, tgt12, Abf);
    // 4. Qrot = rot(tgt1 @ qw.T + qb)
    gemm_q_rot<<<dim3(8, 64), 256, 0, stream>>>(Abf, w_qw, mha_qb, pep_sin, pep_cos, Qrot);
    // 5. kv GEMM with fused k-rotation + v-transpose epilogue
    gemm_kv<<<dim3(8, 128), 256, 0, stream>>>(membf, w_kvw, mha_kvb, pk_sin, pk_cos, Krot, Vth);
    // 6. cross-attention (960 valid keys), KVBLK=128 attn9
    attn9<<<512, 512, 0, stream>>>(Qrot, 512, 64, 0, Krot, 512, 64, 0,
                                   Vth, MM, MM, Abf, MM - 64, 0);
    // 7. tgt2 = LN(x2 @ ow.T + ob + tgt1)
    gemm_bf64<<<dim3(8, 64), 256, 0, stream>>>(Abf, w_mow, mha_ob, utmp, nullptr, nullptr, 512, 512, 0);
    ln_residual<<<8192, 256, 0, stream>>>(utmp, nullptr, tgt12, mha_g, mha_be, tgt12, Abf);
    // 8. h = relu(tgt2 @ w1.T)     (8192x512x2048, bf16 out)
    gemm_bf<<<dim3(16, 64), 256, 0, stream>>>(Abf, w_f1, nullptr, nullptr, hbf, nullptr, 512, 2048, 1);
    // 9. h2 = h @ w2.T  (8192x2048x512) split-K=2, 1024 blocks (4/CU)
    gemm_bf64_sk<<<dim3(8, 64, 2), 256, 0, stream>>>(hbf, w_f2, 2048, 1024, utmp, utmp2, 512);
    // 10. out = LN(tgt2 + h2a + h2b)
    ln_residual<<<8192, 256, 0, stream>>>(utmp, utmp2, tgt12, ffn_g, ffn_be, out, nullptr);
}

// Round 4
// 397.619 us; speedup vs baseline: 1.0711x; 1.0711x over previous
//
#include <hip/hip_runtime.h>
#include <hip/hip_bf16.h>

// Problem constants: B,N,M,HID,NH = 16,512,1024,512,8; HS=64
#define BB 16
#define NN 512
#define MM 1024
#define HIDD 512
#define NHH 8

typedef unsigned short ushort_t;
typedef __attribute__((ext_vector_type(8))) short short8;      // 8 bf16
typedef __attribute__((ext_vector_type(8))) _Float16 half8;    // 8 fp16
typedef __attribute__((ext_vector_type(4))) _Float16 half4;
typedef __attribute__((ext_vector_type(2))) __fp16 fp16x2;     // builtin ret type
typedef __attribute__((ext_vector_type(4))) float f32x4;

__device__ __forceinline__ ushort_t f2bf(float x) {   // RNE fp32->bf16
    unsigned u = __float_as_uint(x);
    u += 0x7fff + ((u >> 16) & 1);
    return (ushort_t)(u >> 16);
}

// async global->LDS, 16B per lane (GEMM staging; layout contiguous per wave)
#define GLD16(g, l) __builtin_amdgcn_global_load_lds(                      \
    (const __attribute__((address_space(1))) void*)(g),                    \
    (__attribute__((address_space(3))) void*)(l), 16, 0, 0)

// XCD-aware swizzle: consecutive linear block ids land on XCD id%8.
__device__ __forceinline__ void xcd_swizzle(int& colb, int& rowb) {
    int id = blockIdx.x + blockIdx.y * gridDim.x;
    int C = gridDim.x;
    int xcd = id & 7;
    int slot = id >> 3;
    int rows_per = gridDim.y >> 3;
    colb = slot % C;
    rowb = xcd * rows_per + slot / C;
}

// ---------------------------------------------------------------------------
// bf16 MFMA GEMM, tile 128x128, BK=32, 4 waves (2x2 of 64x64). Double-buffered.
// ---------------------------------------------------------------------------
__global__ __launch_bounds__(256)
void gemm_bf(const ushort_t* __restrict__ A, const ushort_t* __restrict__ W,
             const float* __restrict__ bias, float* __restrict__ C,
             ushort_t* __restrict__ Cb, _Float16* __restrict__ Ch,
             int K, int Cout, int relu) {
    __shared__ __align__(16) ushort_t smem[2][8192];
    const int tid = threadIdx.x;
    const int lane = tid & 63;
    const int wid = tid >> 6;
    const int wm = wid >> 1, wn = wid & 1;
    int colb, rowb;
    xcd_swizzle(colb, rowb);
    const long row0 = (long)rowb * 128;
    const long col0 = (long)colb * 128;

    const int sr = lane >> 2;
    const int skq = lane & 3;
    const ushort_t* Ag = A + (row0 + wid * 32 + sr) * (long)K + skq * 8;
    const ushort_t* Wg = W + (col0 + wid * 32 + sr) * (long)K + skq * 8;
    const int sa0 = (wid * 32) * 32, sa1 = (wid * 32 + 16) * 32;

    f32x4 acc[4][4] = {};
    const int lr = lane & 15;
    const int kg = lane >> 4;

    GLD16(Ag, &smem[0][sa0]);
    GLD16(Ag + 16 * (long)K, &smem[0][sa1]);
    GLD16(Wg, &smem[0][4096 + sa0]);
    GLD16(Wg + 16 * (long)K, &smem[0][4096 + sa1]);

    int pb = 0;
    for (int k0 = 0; k0 < K; k0 += 32, pb ^= 1) {
        __syncthreads();
        int kn = k0 + 32;
        if (kn < K) {
            GLD16(Ag + kn, &smem[pb ^ 1][sa0]);
            GLD16(Ag + 16 * (long)K + kn, &smem[pb ^ 1][sa1]);
            GLD16(Wg + kn, &smem[pb ^ 1][4096 + sa0]);
            GLD16(Wg + 16 * (long)K + kn, &smem[pb ^ 1][4096 + sa1]);
        }
        const ushort_t* Ab = smem[pb];
        const ushort_t* Wb = smem[pb] + 4096;
        short8 af[4], bfr[4];
#pragma unroll
        for (int i = 0; i < 4; i++)
            af[i] = *(const short8*)&Ab[(wm * 64 + i * 16 + lr) * 32 + kg * 8];
#pragma unroll
        for (int j = 0; j < 4; j++)
            bfr[j] = *(const short8*)&Wb[(wn * 64 + j * 16 + lr) * 32 + kg * 8];
#pragma unroll
        for (int i = 0; i < 4; i++)
#pragma unroll
            for (int j = 0; j < 4; j++)
                acc[i][j] = __builtin_amdgcn_mfma_f32_16x16x32_bf16(
                    af[i], bfr[j], acc[i][j], 0, 0, 0);
    }

#pragma unroll
    for (int i = 0; i < 4; i++) {
#pragma unroll
        for (int j = 0; j < 4; j++) {
            long row = row0 + wm * 64 + i * 16 + kg * 4;
            long col = col0 + wn * 64 + j * 16 + lr;
            float bv = bias ? bias[col] : 0.f;
#pragma unroll
            for (int r = 0; r < 4; r++) {
                float x = acc[i][j][r] + bv;
                if (relu) x = fmaxf(x, 0.f);
                size_t idx = (row + r) * (size_t)Cout + col;
                if (Ch)      Ch[idx] = (_Float16)x;
                else if (Cb) Cb[idx] = f2bf(x);
                else         C[idx] = x;
            }
        }
    }
}

// ---------------------------------------------------------------------------
// bf16 MFMA GEMM, tile 128x64, BK=32, 4 waves, each 32x64. Double-buffered.
// ---------------------------------------------------------------------------
__global__ __launch_bounds__(256)
void gemm_bf64(const ushort_t* __restrict__ A, const ushort_t* __restrict__ W,
               const float* __restrict__ bias, float* __restrict__ C,
               ushort_t* __restrict__ Cb, _Float16* __restrict__ Ch,
               int K, int Cout, int relu) {
    __shared__ __align__(16) ushort_t smem[2][6144];
    const int tid = threadIdx.x;
    const int lane = tid & 63;
    const int w = tid >> 6;
    int colb, rowb;
    xcd_swizzle(colb, rowb);
    const long row0 = (long)rowb * 128;
    const long col0 = (long)colb * 64;

    const int sr = lane >> 2;
    const int skq = lane & 3;
    const ushort_t* Ag = A + (row0 + w * 32 + sr) * (long)K + skq * 8;
    const ushort_t* Wg = W + (col0 + w * 16 + sr) * (long)K + skq * 8;
    const int sa0 = (w * 32) * 32, sa1 = (w * 32 + 16) * 32;
    const int sw0 = 4096 + (w * 16) * 32;

    f32x4 acc[2][4] = {};
    const int lr = lane & 15;
    const int kg = lane >> 4;

    GLD16(Ag, &smem[0][sa0]);
    GLD16(Ag + 16 * (long)K, &smem[0][sa1]);
    GLD16(Wg, &smem[0][sw0]);

    int pb = 0;
    for (int k0 = 0; k0 < K; k0 += 32, pb ^= 1) {
        __syncthreads();
        int kn = k0 + 32;
        if (kn < K) {
            GLD16(Ag + kn, &smem[pb ^ 1][sa0]);
            GLD16(Ag + 16 * (long)K + kn, &smem[pb ^ 1][sa1]);
            GLD16(Wg + kn, &smem[pb ^ 1][sw0]);
        }
        const ushort_t* Ab = smem[pb];
        const ushort_t* Wb = smem[pb] + 4096;
        short8 af[2], bfr[4];
#pragma unroll
        for (int i = 0; i < 2; i++)
            af[i] = *(const short8*)&Ab[(w * 32 + i * 16 + lr) * 32 + kg * 8];
#pragma unroll
        for (int j = 0; j < 4; j++)
            bfr[j] = *(const short8*)&Wb[(j * 16 + lr) * 32 + kg * 8];
#pragma unroll
        for (int i = 0; i < 2; i++)
#pragma unroll
            for (int j = 0; j < 4; j++)
                acc[i][j] = __builtin_amdgcn_mfma_f32_16x16x32_bf16(
                    af[i], bfr[j], acc[i][j], 0, 0, 0);
    }

#pragma unroll
    for (int i = 0; i < 2; i++) {
#pragma unroll
        for (int j = 0; j < 4; j++) {
            long row = row0 + w * 32 + i * 16 + kg * 4;
            long col = col0 + j * 16 + lr;
            float bv = bias ? bias[col] : 0.f;
#pragma unroll
            for (int r = 0; r < 4; r++) {
                float x = acc[i][j][r] + bv;
                if (relu) x = fmaxf(x, 0.f);
                size_t idx = (row + r) * (size_t)Cout + col;
                if (Ch)      Ch[idx] = (_Float16)x;
                else if (Cb) Cb[idx] = f2bf(x);
                else         C[idx] = x;
            }
        }
    }
}

// ---------------------------------------------------------------------------
// gemm_bf64_sk: split-K=2 variant for h @ w2.T (A stride lda, K-slice per z).
// z = blockIdx.z selects k-slice and output buffer (C0 / C1); LN sums them.
// ---------------------------------------------------------------------------
__global__ __launch_bounds__(256)
void gemm_bf64_sk(const ushort_t* __restrict__ A, const ushort_t* __restrict__ W,
                  int lda, int Kslice, float* __restrict__ C0,
                  float* __restrict__ C1, int Cout) {
    __shared__ __align__(16) ushort_t smem[2][6144];
    const int tid = threadIdx.x;
    const int lane = tid & 63;
    const int w = tid >> 6;
    int colb, rowb;
    xcd_swizzle(colb, rowb);
    const long row0 = (long)rowb * 128;
    const long col0 = (long)colb * 64;
    const long koff = (long)blockIdx.z * Kslice;
    float* __restrict__ C = blockIdx.z ? C1 : C0;

    const int sr = lane >> 2;
    const int skq = lane & 3;
    const ushort_t* Ag = A + (row0 + w * 32 + sr) * (long)lda + koff + skq * 8;
    const ushort_t* Wg = W + (col0 + w * 16 + sr) * (long)lda + koff + skq * 8;
    const int sa0 = (w * 32) * 32, sa1 = (w * 32 + 16) * 32;
    const int sw0 = 4096 + (w * 16) * 32;

    f32x4 acc[2][4] = {};
    const int lr = lane & 15;
    const int kg = lane >> 4;

    GLD16(Ag, &smem[0][sa0]);
    GLD16(Ag + 16 * (long)lda, &smem[0][sa1]);
    GLD16(Wg, &smem[0][sw0]);

    int pb = 0;
    for (int k0 = 0; k0 < Kslice; k0 += 32, pb ^= 1) {
        __syncthreads();
        int kn = k0 + 32;
        if (kn < Kslice) {
            GLD16(Ag + kn, &smem[pb ^ 1][sa0]);
            GLD16(Ag + 16 * (long)lda + kn, &smem[pb ^ 1][sa1]);
            GLD16(Wg + kn, &smem[pb ^ 1][sw0]);
        }
        const ushort_t* Ab = smem[pb];
        const ushort_t* Wb = smem[pb] + 4096;
        short8 af[2], bfr[4];
#pragma unroll
        for (int i = 0; i < 2; i++)
            af[i] = *(const short8*)&Ab[(w * 32 + i * 16 + lr) * 32 + kg * 8];
#pragma unroll
        for (int j = 0; j < 4; j++)
            bfr[j] = *(const short8*)&Wb[(j * 16 + lr) * 32 + kg * 8];
#pragma unroll
        for (int i = 0; i < 2; i++)
#pragma unroll
            for (int j = 0; j < 4; j++)
                acc[i][j] = __builtin_amdgcn_mfma_f32_16x16x32_bf16(
                    af[i], bfr[j], acc[i][j], 0, 0, 0);
    }

#pragma unroll
    for (int i = 0; i < 2; i++)
#pragma unroll
        for (int j = 0; j < 4; j++) {
            long row = row0 + w * 32 + i * 16 + kg * 4;
            long col = col0 + j * 16 + lr;
#pragma unroll
            for (int r = 0; r < 4; r++)
                C[(row + r) * (size_t)Cout + col] = acc[i][j][r];
        }
}

// ---------------------------------------------------------------------------
// gemm_q_rot: 128x64-tile GEMM (Cout=512, K=512), col-block = one head.
// Double-buffered; epilogue Cs overlays staging LDS; rotates -> Qrot f16.
// ---------------------------------------------------------------------------
__global__ __launch_bounds__(256)
void gemm_q_rot(const ushort_t* __restrict__ A, const ushort_t* __restrict__ W,
                const float* __restrict__ bias,
                const float* __restrict__ sn, const float* __restrict__ cs,
                _Float16* __restrict__ Qrot) {
    __shared__ __align__(16) ushort_t smem[2][6144];
    _Float16* Cs = (_Float16*)smem;
    const int K = 512;
    const int tid = threadIdx.x;
    const int lane = tid & 63;
    const int w = tid >> 6;
    int colb, rowb;
    xcd_swizzle(colb, rowb);
    const long row0 = (long)rowb * 128;
    const int h = colb;
    const long col0 = (long)h * 64;

    const int sr = lane >> 2;
    const int skq = lane & 3;
    const ushort_t* Ag = A + (row0 + w * 32 + sr) * (long)K + skq * 8;
    const ushort_t* Wg = W + (col0 + w * 16 + sr) * (long)K + skq * 8;
    const int sa0 = (w * 32) * 32, sa1 = (w * 32 + 16) * 32;
    const int sw0 = 4096 + (w * 16) * 32;

    f32x4 acc[2][4] = {};
    const int lr = lane & 15;
    const int kg = lane >> 4;

    GLD16(Ag, &smem[0][sa0]);
    GLD16(Ag + 16 * (long)K, &smem[0][sa1]);
    GLD16(Wg, &smem[0][sw0]);

    int pb = 0;
    for (int k0 = 0; k0 < K; k0 += 32, pb ^= 1) {
        __syncthreads();
        int kn = k0 + 32;
        if (kn < K) {
            GLD16(Ag + kn, &smem[pb ^ 1][sa0]);
            GLD16(Ag + 16 * (long)K + kn, &smem[pb ^ 1][sa1]);
            GLD16(Wg + kn, &smem[pb ^ 1][sw0]);
        }
        const ushort_t* Ab = smem[pb];
        const ushort_t* Wb = smem[pb] + 4096;
        short8 af[2], bfr[4];
#pragma unroll
        for (int i = 0; i < 2; i++)
            af[i] = *(const short8*)&Ab[(w * 32 + i * 16 + lr) * 32 + kg * 8];
#pragma unroll
        for (int j = 0; j < 4; j++)
            bfr[j] = *(const short8*)&Wb[(j * 16 + lr) * 32 + kg * 8];
#pragma unroll
        for (int i = 0; i < 2; i++)
#pragma unroll
            for (int j = 0; j < 4; j++)
                acc[i][j] = __builtin_amdgcn_mfma_f32_16x16x32_bf16(
                    af[i], bfr[j], acc[i][j], 0, 0, 0);
    }

    __syncthreads();
#pragma unroll
    for (int i = 0; i < 2; i++)
#pragma unroll
        for (int j = 0; j < 4; j++) {
            int row = w * 32 + i * 16 + kg * 4;
            int col = j * 16 + lr;
            float bv = bias[col0 + col];
#pragma unroll
            for (int r = 0; r < 4; r++)
                Cs[(row + r) * 76 + col] = (_Float16)(acc[i][j][r] + bv);
        }
    __syncthreads();
    for (int idx = tid; idx < 4096; idx += 256) {
        int rr = idx >> 5, j = idx & 31;
        size_t srow = (size_t)row0 + rr;
        float x0 = (float)Cs[rr * 76 + 2 * j], x1 = (float)Cs[rr * 76 + 2 * j + 1];
        float s = sn[srow * 32 + j], c = cs[srow * 32 + j];
        Qrot[srow * 512 + h * 64 + j]      = (_Float16)(x0 * c - x1 * s);
        Qrot[srow * 512 + h * 64 + 32 + j] = (_Float16)(x1 * c + x0 * s);
    }
}

// ---------------------------------------------------------------------------
// gemm_kv: 128x128-tile GEMM (Cout=1024, K=512), col-block = one head's k|v.
// Double-buffered; epilogue: rotate k -> Krot, transpose v -> Vth.
// ---------------------------------------------------------------------------
__global__ __launch_bounds__(256)
void gemm_kv(const ushort_t* __restrict__ A, const ushort_t* __restrict__ W,
             const float* __restrict__ bias,
             const float* __restrict__ sn, const float* __restrict__ cs,
             _Float16* __restrict__ Krot, _Float16* __restrict__ Vth) {
    __shared__ __align__(16) ushort_t smem[2][8192];
    _Float16* Cs = (_Float16*)smem;
    const int K = 512;
    const int tid = threadIdx.x;
    const int lane = tid & 63;
    const int wid = tid >> 6;
    const int wm = wid >> 1, wn = wid & 1;
    int colb, rowb;
    xcd_swizzle(colb, rowb);
    const long row0 = (long)rowb * 128;
    const int h = colb;
    const long col0 = (long)h * 128;

    const int sr = lane >> 2;
    const int skq = lane & 3;
    const ushort_t* Ag = A + (row0 + wid * 32 + sr) * (long)K + skq * 8;
    const ushort_t* Wg = W + (col0 + wid * 32 + sr) * (long)K + skq * 8;
    const int sa0 = (wid * 32) * 32, sa1 = (wid * 32 + 16) * 32;

    f32x4 acc[4][4] = {};
    const int lr = lane & 15;
    const int kg = lane >> 4;

    GLD16(Ag, &smem[0][sa0]);
    GLD16(Ag + 16 * (long)K, &smem[0][sa1]);
    GLD16(Wg, &smem[0][4096 + sa0]);
    GLD16(Wg + 16 * (long)K, &smem[0][4096 + sa1]);

    int pb = 0;
    for (int k0 = 0; k0 < K; k0 += 32, pb ^= 1) {
        __syncthreads();
        int kn = k0 + 32;
        if (kn < K) {
            GLD16(Ag + kn, &smem[pb ^ 1][sa0]);
            GLD16(Ag + 16 * (long)K + kn, &smem[pb ^ 1][sa1]);
            GLD16(Wg + kn, &smem[pb ^ 1][4096 + sa0]);
            GLD16(Wg + 16 * (long)K + kn, &smem[pb ^ 1][4096 + sa1]);
        }
        const ushort_t* Ab = smem[pb];
        const ushort_t* Wb = smem[pb] + 4096;
        short8 af[4], bfr[4];
#pragma unroll
        for (int i = 0; i < 4; i++)
            af[i] = *(const short8*)&Ab[(wm * 64 + i * 16 + lr) * 32 + kg * 8];
#pragma unroll
        for (int j = 0; j < 4; j++)
            bfr[j] = *(const short8*)&Wb[(wn * 64 + j * 16 + lr) * 32 + kg * 8];
#pragma unroll
        for (int i = 0; i < 4; i++)
#pragma unroll
            for (int j = 0; j < 4; j++)
                acc[i][j] = __builtin_amdgcn_mfma_f32_16x16x32_bf16(
                    af[i], bfr[j], acc[i][j], 0, 0, 0);
    }

    const int b_ = (int)(row0 >> 10);
    const int m0_ = (int)(row0 & 1023);
#pragma unroll
    for (int half = 0; half < 2; half++) {
        __syncthreads();
        if (wn == half) {
#pragma unroll
            for (int i = 0; i < 4; i++)
#pragma unroll
                for (int j = 0; j < 4; j++) {
                    int row = wm * 64 + i * 16 + kg * 4;
                    int col = j * 16 + lr;
                    float bv = bias[col0 + half * 64 + col];
#pragma unroll
                    for (int r = 0; r < 4; r++)
                        Cs[(row + r) * 76 + col] = (_Float16)(acc[i][j][r] + bv);
                }
        }
        __syncthreads();
        if (half == 0) {
            for (int idx = tid; idx < 4096; idx += 256) {
                int rr = idx >> 5, j = idx & 31;
                size_t srow = (size_t)row0 + rr;
                float x0 = (float)Cs[rr * 76 + 2 * j], x1 = (float)Cs[rr * 76 + 2 * j + 1];
                float s = sn[srow * 32 + j], c = cs[srow * 32 + j];
                Krot[srow * 512 + h * 64 + j]      = (_Float16)(x0 * c - x1 * s);
                Krot[srow * 512 + h * 64 + 32 + j] = (_Float16)(x1 * c + x0 * s);
            }
        } else {
            for (int idx = tid; idx < 1024; idx += 256) {
                int d = idx >> 4, c = idx & 15;
                half8 v;
#pragma unroll
                for (int k = 0; k < 8; k++) v[k] = Cs[(c * 8 + k) * 76 + d];
                *(half8*)(Vth + (((size_t)(b_ * NHH + h)) * 64 + d) * MM
                          + m0_ + c * 8) = v;
            }
        }
    }
}

// ---------------------------------------------------------------------------
// One-shot fp32->bf16 convert of tgt, mem, and all 7 weight mats.
// ---------------------------------------------------------------------------
__global__ __launch_bounds__(256)
void cvt_all(const float* __restrict__ tgt, const float* __restrict__ mem,
             const float* __restrict__ w0, const float* __restrict__ w1,
             const float* __restrict__ w2, const float* __restrict__ w3,
             const float* __restrict__ w4, const float* __restrict__ w5,
             const float* __restrict__ w6,
             ushort_t* __restrict__ Abf, ushort_t* __restrict__ membf,
             ushort_t* __restrict__ Wbf) {
    int blk = blockIdx.x;
    const float* src;
    ushort_t* dst;
    size_t off;
    if (blk < 4096)       { src = tgt; dst = Abf;   off = (size_t)blk * 1024; }
    else if (blk < 12288) { src = mem; dst = membf; off = (size_t)(blk - 4096) * 1024; }
    else {
        int wb = blk - 12288;
        dst = Wbf + (size_t)wb * 1024;
        if (wb < 768)       { src = w0; off = (size_t)wb * 1024; }
        else if (wb < 1024) { src = w1; off = (size_t)(wb - 768) * 1024; }
        else if (wb < 1280) { src = w2; off = (size_t)(wb - 1024) * 1024; }
        else if (wb < 1792) { src = w3; off = (size_t)(wb - 1280) * 1024; }
        else if (wb < 2048) { src = w4; off = (size_t)(wb - 1792) * 1024; }
        else if (wb < 3072) { src = w5; off = (size_t)(wb - 2048) * 1024; }
        else                { src = w6; off = (size_t)(wb - 3072) * 1024; }
        float4 v = *(const float4*)(src + off + threadIdx.x * 4);
        ushort4 o;
        o.x = f2bf(v.x); o.y = f2bf(v.y); o.z = f2bf(v.z); o.w = f2bf(v.w);
        *(ushort4*)(dst + threadIdx.x * 4) = o;
        return;
    }
    float4 v = *(const float4*)(src + off + threadIdx.x * 4);
    ushort4 o;
    o.x = f2bf(v.x); o.y = f2bf(v.y); o.z = f2bf(v.z); o.w = f2bf(v.w);
    *(ushort4*)(dst + off + threadIdx.x * 4) = o;
}

// ---------------------------------------------------------------------------
// prep_vt: transpose 64-wide V slice per head (self-attention path).
// ---------------------------------------------------------------------------
__global__ __launch_bounds__(256)
void prep_vt(const _Float16* __restrict__ src, int L, int stride,
             int hmul, int hadd, _Float16* __restrict__ Vt) {
    const int b = blockIdx.z, h = blockIdx.y, m0 = blockIdx.x * 64;
    const int tid = threadIdx.x;
    __shared__ _Float16 vt[64][72];
    for (int idx = tid; idx < 512; idx += 256) {
        int m = idx >> 3, c = idx & 7;
        half8 v = *(const half8*)(src + ((size_t)(b * L + m0 + m)) * stride
                                  + h * hmul + hadd + c * 8);
#pragma unroll
        for (int k = 0; k < 8; k++) vt[c * 8 + k][m] = v[k];
    }
    __syncthreads();
    for (int idx = tid; idx < 512; idx += 256) {
        int d = idx >> 3, c = idx & 7;
        *(half8*)(Vt + (((size_t)(b * NHH + h)) * 64 + d) * L + m0 + c * 8)
            = *(const half8*)&vt[d][c * 8];
    }
}

// ---------------------------------------------------------------------------
// Flash MFMA attention v10 = v8 structure (KVBLK=64, 44 VGPR, no spill —
// v9's KVBLK=128 spilled to scratch: WRITE_SIZE 8->37MB, +30% dur) plus:
// (a) keep-test on per-lane PARTIAL max (__all covers the row) -> the
//     2-shuffle max reduce only runs on the rare !keep path;
// (b) lrun kept as per-lane partial (corr is row-uniform so rescaling
//     partials is valid), reduced ONCE at the end -> -2 shuffles/tile;
// (c) v_cvt_pkrtz packs P pairs in 1 VALU op (ret type is __fp16x2;
//     bit-cast into the half4 store);
// (d) causal load-balance: co-resident blocks i,i+256 get qb pairs
//     (0,3),(1,2) = 10/10 tile-units instead of (0,2),(1,3) = 8/12.
// ---------------------------------------------------------------------------
__global__ __launch_bounds__(512, 4)
void attn10(const _Float16* __restrict__ Q, int qstride, int qmul, int qadd,
            const _Float16* __restrict__ K, int kstride, int kmul, int kadd,
            const _Float16* __restrict__ Vt, int LV, int Lrows,
            ushort_t* __restrict__ out, int kvlen, int causal) {
    const int g = blockIdx.x;
    const int bh = (g & 7) * 16 + ((g >> 3) & 15);
    int qb = g >> 7;
    qb ^= (qb & 2) >> 1;                            // perm [0,1,3,2]: balance pairs
    const int b = bh >> 3, h = bh & 7;
    const int n0 = qb * 128;
    const int tid = threadIdx.x, lane = tid & 63, w = tid >> 6;
    const int quad = lane >> 4, l16 = lane & 15;
    const int qw = n0 + w * 16;                     // 16 q rows per wave

    __shared__ _Float16 Ks[2][64 * 64];
    __shared__ _Float16 Vs[2][64 * 64];
    __shared__ _Float16 Ps[8][16 * 64];
    _Float16* Pw = Ps[w];

    half8 bq[2];
#pragma unroll
    for (int c = 0; c < 2; c++)
        bq[c] = *(const half8*)(Q + ((size_t)(b * NN + qw + l16)) * qstride
                                + h * qmul + qadd + c * 32 + quad * 8);

    f32x4 acc[4] = {};
    float mrun = -3e38f, lrun = 0.f;                // lrun is a per-lane PARTIAL

    const int srow = tid >> 3;                      // 0..63 (512 threads)
    const int scol = tid & 7;                       // chunk index 0..7
    const int ssw = (scol ^ (srow & 7)) * 8;        // swizzled chunk offset

    const int limit = causal ? (n0 + 128) : kvlen;
    const int nt = limit >> 6;

    const size_t kbase = ((size_t)(b * Lrows)) * kstride + h * kmul + kadd;
    const size_t vbase = (((size_t)(b * NHH + h)) * 64 + srow) * (size_t)LV;

    // prologue: tile 0 -> LDS buf0; issue tile 1 loads into regs
    half8 kr = *(const half8*)(K + kbase + (size_t)srow * kstride + scol * 8);
    half8 vr = *(const half8*)(Vt + vbase + scol * 8);
    *(half8*)&Ks[0][srow * 64 + ssw] = kr;
    *(half8*)&Vs[0][srow * 64 + ssw] = vr;
    if (nt > 1) {
        kr = *(const half8*)(K + kbase + (size_t)(64 + srow) * kstride + scol * 8);
        vr = *(const half8*)(Vt + vbase + 64 + scol * 8);
    }

    const float SC = 0.125f * 1.44269504f;          // scale * log2(e)
    const int fsw = l16 & 7;                        // frag-read row swizzle
    int pb = 0;
    for (int t = 0; t < nt; t++, pb ^= 1) {
        const int key0 = t * 64;
        __syncthreads();                            // buf[pb] ready; prior reads of buf[pb^1] done
        if (t + 1 < nt) {
            // write tile t+1 (loaded one full iteration ago) to the other buffer
            *(half8*)&Ks[pb ^ 1][srow * 64 + ssw] = kr;
            *(half8*)&Vs[pb ^ 1][srow * 64 + ssw] = vr;
            if (t + 2 < nt) {                       // issue tile t+2 loads
                kr = *(const half8*)(K + kbase
                        + (size_t)((t + 2) * 64 + srow) * kstride + scol * 8);
                vr = *(const half8*)(Vt + vbase + (t + 2) * 64 + scol * 8);
            }
        }
        if (causal && key0 > qw + 15) continue;     // wave fully masked

        const _Float16* Kb = Ks[pb];
        const _Float16* Vb = Vs[pb];
        f32x4 st[4];
        __builtin_amdgcn_s_setprio(1);
#pragma unroll
        for (int kt = 0; kt < 4; kt++) {
            const int rk = kt * 16 + l16;
            half8 ak0 = *(const half8*)&Kb[rk * 64 + ((quad ^ fsw) * 8)];
            half8 ak1 = *(const half8*)&Kb[rk * 64 + (((quad + 4) ^ fsw) * 8)];
            f32x4 z = {};
            z = __builtin_amdgcn_mfma_f32_16x16x32_f16(ak0, bq[0], z, 0, 0, 0);
            z = __builtin_amdgcn_mfma_f32_16x16x32_f16(ak1, bq[1], z, 0, 0, 0);
            st[kt] = z;
        }
        __builtin_amdgcn_s_setprio(0);

        if (causal && key0 + 64 > qw) {
            const int qabs = qw + l16;
#pragma unroll
            for (int kt = 0; kt < 4; kt++)
#pragma unroll
                for (int r = 0; r < 4; r++)
                    if (key0 + kt * 16 + quad * 4 + r > qabs)
                        st[kt][r] = -3e38f;
        }

        // per-lane partial max over this lane's 16 scores
        float plm = -3e38f;
#pragma unroll
        for (int kt = 0; kt < 4; kt++)
            plm = fmaxf(plm, fmaxf(fmaxf(st[kt][0], st[kt][1]),
                                   fmaxf(st[kt][2], st[kt][3])));

        // defer-max on partial max: if every lane's partial is within THR of
        // mrun, every row max is too (THR=64 raw = 8 post-scale; P<=e^8 fits
        // f16). No cross-lane reduce on the common path.
        const int keep = __all(plm - mrun <= 64.f);
        if (!keep) {
            float lm = fmaxf(plm, __shfl_xor(plm, 16));
            lm = fmaxf(lm, __shfl_xor(lm, 32));
            float mnew = fmaxf(mrun, lm);
            float corr = exp2f((mrun - mnew) * SC);
            mrun = mnew;
            lrun *= corr;                           // partial-lrun rescale valid: corr row-uniform
            float cb0 = __shfl(corr, (lane & 48) | (quad * 4 + 0));
            float cb1 = __shfl(corr, (lane & 48) | (quad * 4 + 1));
            float cb2 = __shfl(corr, (lane & 48) | (quad * 4 + 2));
            float cb3 = __shfl(corr, (lane & 48) | (quad * 4 + 3));
#pragma unroll
            for (int dt = 0; dt < 4; dt++) {
                acc[dt][0] *= cb0; acc[dt][1] *= cb1;
                acc[dt][2] *= cb2; acc[dt][3] *= cb3;
            }
        }
        const float mb = mrun * SC;
#pragma unroll
        for (int kt = 0; kt < 4; kt++) {
            float p0 = exp2f(__builtin_fmaf(st[kt][0], SC, -mb));
            float p1 = exp2f(__builtin_fmaf(st[kt][1], SC, -mb));
            float p2 = exp2f(__builtin_fmaf(st[kt][2], SC, -mb));
            float p3 = exp2f(__builtin_fmaf(st[kt][3], SC, -mb));
            lrun += (p0 + p1) + (p2 + p3);
            fp16x2 lo = __builtin_amdgcn_cvt_pkrtz(p0, p1);
            fp16x2 hi = __builtin_amdgcn_cvt_pkrtz(p2, p3);
            union { unsigned u[2]; half4 h; } pk;
            pk.u[0] = __builtin_bit_cast(unsigned, lo);
            pk.u[1] = __builtin_bit_cast(unsigned, hi);
            int jc = 2 * kt + (quad >> 1);
            *(half4*)&Pw[l16 * 64 + ((jc ^ fsw) * 8) + (quad & 1) * 4] = pk.h;
        }
        half8 ap[2];
#pragma unroll
        for (int c = 0; c < 2; c++)
            ap[c] = *(const half8*)&Pw[l16 * 64 + (((c * 4 + quad) ^ fsw) * 8)];
        __builtin_amdgcn_s_setprio(1);
#pragma unroll
        for (int dt = 0; dt < 4; dt++) {
            const int rv = dt * 16 + l16;
            half8 bv0 = *(const half8*)&Vb[rv * 64 + ((quad ^ fsw) * 8)];
            half8 bv1 = *(const half8*)&Vb[rv * 64 + (((quad + 4) ^ fsw) * 8)];
            acc[dt] = __builtin_amdgcn_mfma_f32_16x16x32_f16(ap[0], bv0, acc[dt], 0, 0, 0);
            acc[dt] = __builtin_amdgcn_mfma_f32_16x16x32_f16(ap[1], bv1, acc[dt], 0, 0, 0);
        }
        __builtin_amdgcn_s_setprio(0);
    }

    // final lrun reduce (deferred from per-tile): sum partials across quads
    lrun += __shfl_xor(lrun, 16);
    lrun += __shfl_xor(lrun, 32);
    float invq = 1.f / lrun;
    float iv0 = __shfl(invq, (lane & 48) | (quad * 4 + 0));
    float iv1 = __shfl(invq, (lane & 48) | (quad * 4 + 1));
    float iv2 = __shfl(invq, (lane & 48) | (quad * 4 + 2));
    float iv3 = __shfl(invq, (lane & 48) | (quad * 4 + 3));
#pragma unroll
    for (int dt = 0; dt < 4; dt++) {
        size_t base = ((size_t)(b * NN + qw + quad * 4)) * 512
                      + h * 64 + dt * 16 + l16;
        out[base]           = f2bf(acc[dt][0] * iv0);
        out[base + 512]     = f2bf(acc[dt][1] * iv1);
        out[base + 1024]    = f2bf(acc[dt][2] * iv2);
        out[base + 1536]    = f2bf(acc[dt][3] * iv3);
    }
}

// ---------------------------------------------------------------------------
// out = LayerNorm(u + (u2?) + res)*g + beta; optional bf16 copy.
// ---------------------------------------------------------------------------
__global__ __launch_bounds__(256)
void ln_residual(const float* __restrict__ u, const float* __restrict__ u2,
                 const float* __restrict__ res,
                 const float* __restrict__ g, const float* __restrict__ be,
                 float* __restrict__ out, ushort_t* __restrict__ outbf) {
    const int row = blockIdx.x, t = threadIdx.x;
    const float* rp = res + (size_t)row * HIDD;
    const float* up = u + (size_t)row * HIDD;
    float z0 = rp[t] + up[t];
    float z1 = rp[t + 256] + up[t + 256];
    if (u2) {
        const float* up2 = u2 + (size_t)row * HIDD;
        z0 += up2[t];
        z1 += up2[t + 256];
    }
    float sm = z0 + z1, s2 = z0 * z0 + z1 * z1;
#pragma unroll
    for (int off = 1; off < 64; off <<= 1) {
        sm += __shfl_xor(sm, off, 64);
        s2 += __shfl_xor(s2, off, 64);
    }
    __shared__ float ps[4], ps2[4];
    int w = t >> 6;
    if ((t & 63) == 0) { ps[w] = sm; ps2[w] = s2; }
    __syncthreads();
    sm = ps[0] + ps[1] + ps[2] + ps[3];
    s2 = ps2[0] + ps2[1] + ps2[2] + ps2[3];
    float mu = sm * (1.f / 512.f);
    float var = s2 * (1.f / 512.f) - mu * mu;
    float rstd = rsqrtf(var + 1e-5f);
    float y0 = (z0 - mu) * rstd * g[t] + be[t];
    float y1 = (z1 - mu) * rstd * g[t + 256] + be[t + 256];
    out[(size_t)row * HIDD + t]       = y0;
    out[(size_t)row * HIDD + t + 256] = y1;
    if (outbf) {
        outbf[(size_t)row * HIDD + t]       = f2bf(y0);
        outbf[(size_t)row * HIDD + t + 256] = f2bf(y1);
    }
}

// ---------------------------------------------------------------------------
extern "C" void kernel_launch(void* const* d_in, const int* in_sizes, int n_in,
                              void* d_out, int out_size, void* d_ws, size_t ws_size,
                              hipStream_t stream) {
    const float* tgt      = (const float*)d_in[0];
    const float* mem      = (const float*)d_in[1];
    const float* pep_sin  = (const float*)d_in[2];
    const float* pep_cos  = (const float*)d_in[3];
    const float* pk_sin   = (const float*)d_in[4];
    const float* pk_cos   = (const float*)d_in[5];
    const float* mmha_w   = (const float*)d_in[8];
    const float* mmha_b   = (const float*)d_in[9];
    const float* mmha_ow  = (const float*)d_in[10];
    const float* mmha_ob  = (const float*)d_in[11];
    const float* mmha_g   = (const float*)d_in[12];
    const float* mmha_be  = (const float*)d_in[13];
    const float* mha_qw   = (const float*)d_in[14];
    const float* mha_qb   = (const float*)d_in[15];
    const float* mha_kvw  = (const float*)d_in[16];
    const float* mha_kvb  = (const float*)d_in[17];
    const float* mha_ow   = (const float*)d_in[18];
    const float* mha_ob   = (const float*)d_in[19];
    const float* mha_g    = (const float*)d_in[20];
    const float* mha_be   = (const float*)d_in[21];
    const float* ffn_w1   = (const float*)d_in[22];
    const float* ffn_w2   = (const float*)d_in[23];
    const float* ffn_g    = (const float*)d_in[24];
    const float* ffn_be   = (const float*)d_in[25];

    float* ws = (float*)d_ws;
    float* utmp  = ws;                        //  4,194,304 f32
    float* tgt12 = ws + 4194304;              //  4,194,304 f32
    _Float16* hp = (_Float16*)(ws + 8388608); // half pool (offsets in halves)
    _Float16* qkvh  = hp;                     // 12,582,912 (B*N*1536)
    _Float16* Qrot  = hp + 12582912;          //  4,194,304
    _Float16* Vth   = hp + 16777216;          //  8,388,608 (self uses half)
    _Float16* Krot  = hp + 25165824;          //  8,388,608
    ushort_t* membf = (ushort_t*)(hp + 33554432); // 8,388,608 bf16
    ushort_t* Abf   = (ushort_t*)(hp + 41943040); // 4,194,304 bf16
    ushort_t* Wbf   = (ushort_t*)(hp + 46137344); // 4,194,304 bf16 weights
    ushort_t* w_mmha = Wbf;                   //   786,432
    ushort_t* w_mmow = Wbf + 786432;          //   262,144
    ushort_t* w_qw   = Wbf + 1048576;         //   262,144
    ushort_t* w_kvw  = Wbf + 1310720;         //   524,288
    ushort_t* w_mow  = Wbf + 1835008;         //   262,144
    ushort_t* w_f1   = Wbf + 2097152;         // 1,048,576
    ushort_t* w_f2   = Wbf + 3145728;         // 1,048,576
    ushort_t* hbf = (ushort_t*)qkvh;          // ffn hidden bf16 spans qkvh+Qrot
    float* utmp2 = (float*)Krot;              // dead after cross-attn; split-K slice 1
    float* out = (float*)d_out;
    (void)in_sizes; (void)n_in; (void)out_size; (void)ws_size;

    // 0. all fp32->bf16 converts in one launch
    cvt_all<<<16384, 256, 0, stream>>>(tgt, mem, mmha_w, mmha_ow, mha_qw,
                                       mha_kvw, mha_ow, ffn_w1, ffn_w2,
                                       Abf, membf, Wbf);
    // 1. qkv = tgt @ mmha_w.T + b  (8192x512x1536, f16 out)
    gemm_bf<<<dim3(12, 64), 256, 0, stream>>>(Abf, w_mmha, mmha_b, nullptr, nullptr, qkvh, 512, 1536, 0);
    // 2. self-attention (causal), v10
    prep_vt<<<dim3(8, NHH, BB), 256, 0, stream>>>(qkvh, NN, 1536, 192, 128, Vth);
    attn10<<<512, 512, 0, stream>>>(qkvh, 1536, 192, 0, qkvh, 1536, 192, 64,
                                    Vth, NN, NN, Abf, 0, 1);
    // 3. tgt1 = LN(x @ ow.T + ob + tgt)
    gemm_bf64<<<dim3(8, 64), 256, 0, stream>>>(Abf, w_mmow, mmha_ob, utmp, nullptr, nullptr, 512, 512, 0);
    ln_residual<<<8192, 256, 0, stream>>>(utmp, nullptr, tgt, mmha_g, mmha_be, tgt12, Abf);
    // 4. Qrot = rot(tgt1 @ qw.T + qb)
    gemm_q_rot<<<dim3(8, 64), 256, 0, stream>>>(Abf, w_qw, mha_qb, pep_sin, pep_cos, Qrot);
    // 5. kv GEMM with fused k-rotation + v-transpose epilogue
    gemm_kv<<<dim3(8, 128), 256, 0, stream>>>(membf, w_kvw, mha_kvb, pk_sin, pk_cos, Krot, Vth);
    // 6. cross-attention (960 valid keys), v10
    attn10<<<512, 512, 0, stream>>>(Qrot, 512, 64, 0, Krot, 512, 64, 0,
                                    Vth, MM, MM, Abf, MM - 64, 0);
    // 7. tgt2 = LN(x2 @ ow.T + ob + tgt1)
    gemm_bf64<<<dim3(8, 64), 256, 0, stream>>>(Abf, w_mow, mha_ob, utmp, nullptr, nullptr, 512, 512, 0);
    ln_residual<<<8192, 256, 0, stream>>>(utmp, nullptr, tgt12, mha_g, mha_be, tgt12, Abf);
    // 8. h = relu(tgt2 @ w1.T)     (8192x512x2048, bf16 out)
    gemm_bf<<<dim3(16, 64), 256, 0, stream>>>(Abf, w_f1, nullptr, nullptr, hbf, nullptr, 512, 2048, 1);
    // 9. h2 = h @ w2.T  (8192x2048x512) split-K=2, 1024 blocks
    gemm_bf64_sk<<<dim3(8, 64, 2), 256, 0, stream>>>(hbf, w_f2, 2048, 1024, utmp, utmp2, 512);
    // 10. out = LN(tgt2 + h2a + h2b)
    ln_residual<<<8192, 256, 0, stream>>>(utmp, utmp2, tgt12, ffn_g, ffn_be, out, nullptr);
}

// Round 6
// 394.993 us; speedup vs baseline: 1.0782x; 1.0066x over previous
//
#include <hip/hip_runtime.h>
#include <hip/hip_bf16.h>

// Problem constants: B,N,M,HID,NH = 16,512,1024,512,8; HS=64
#define BB 16
#define NN 512
#define MM 1024
#define HIDD 512
#define NHH 8

typedef unsigned short ushort_t;
typedef __attribute__((ext_vector_type(8))) short short8;      // 8 bf16
typedef __attribute__((ext_vector_type(8))) _Float16 half8;    // 8 fp16
typedef __attribute__((ext_vector_type(4))) _Float16 half4;
typedef __attribute__((ext_vector_type(2))) __fp16 fp16x2;     // builtin ret type
typedef __attribute__((ext_vector_type(4))) float f32x4;

__device__ __forceinline__ ushort_t f2bf(float x) {   // RNE fp32->bf16
    unsigned u = __float_as_uint(x);
    u += 0x7fff + ((u >> 16) & 1);
    return (ushort_t)(u >> 16);
}

// async global->LDS, 16B per lane (GEMM staging; layout contiguous per wave)
#define GLD16(g, l) __builtin_amdgcn_global_load_lds(                      \
    (const __attribute__((address_space(1))) void*)(g),                    \
    (__attribute__((address_space(3))) void*)(l), 16, 0, 0)

// XCD-aware swizzle: consecutive linear block ids land on XCD id%8.
__device__ __forceinline__ void xcd_swizzle(int& colb, int& rowb) {
    int id = blockIdx.x + blockIdx.y * gridDim.x;
    int C = gridDim.x;
    int xcd = id & 7;
    int slot = id >> 3;
    int rows_per = gridDim.y >> 3;
    colb = slot % C;
    rowb = xcd * rows_per + slot / C;
}

// parameterized variant for merged/1-D launches (R must be multiple of 8)
__device__ __forceinline__ void xcd_swz_p(int id, int C, int Rdiv8,
                                          int& colb, int& rowb) {
    int xcd = id & 7;
    int slot = id >> 3;
    colb = slot % C;
    rowb = xcd * Rdiv8 + slot / C;
}

// ---------------------------------------------------------------------------
// bf16 MFMA GEMM, tile 128x128, BK=32, 4 waves (2x2 of 64x64). Double-buffered.
// ---------------------------------------------------------------------------
__global__ __launch_bounds__(256)
void gemm_bf(const ushort_t* __restrict__ A, const ushort_t* __restrict__ W,
             const float* __restrict__ bias, float* __restrict__ C,
             ushort_t* __restrict__ Cb, _Float16* __restrict__ Ch,
             int K, int Cout, int relu) {
    __shared__ __align__(16) ushort_t smem[2][8192];
    const int tid = threadIdx.x;
    const int lane = tid & 63;
    const int wid = tid >> 6;
    const int wm = wid >> 1, wn = wid & 1;
    int colb, rowb;
    xcd_swizzle(colb, rowb);
    const long row0 = (long)rowb * 128;
    const long col0 = (long)colb * 128;

    const int sr = lane >> 2;
    const int skq = lane & 3;
    const ushort_t* Ag = A + (row0 + wid * 32 + sr) * (long)K + skq * 8;
    const ushort_t* Wg = W + (col0 + wid * 32 + sr) * (long)K + skq * 8;
    const int sa0 = (wid * 32) * 32, sa1 = (wid * 32 + 16) * 32;

    f32x4 acc[4][4] = {};
    const int lr = lane & 15;
    const int kg = lane >> 4;

    GLD16(Ag, &smem[0][sa0]);
    GLD16(Ag + 16 * (long)K, &smem[0][sa1]);
    GLD16(Wg, &smem[0][4096 + sa0]);
    GLD16(Wg + 16 * (long)K, &smem[0][4096 + sa1]);

    int pb = 0;
    for (int k0 = 0; k0 < K; k0 += 32, pb ^= 1) {
        __syncthreads();
        int kn = k0 + 32;
        if (kn < K) {
            GLD16(Ag + kn, &smem[pb ^ 1][sa0]);
            GLD16(Ag + 16 * (long)K + kn, &smem[pb ^ 1][sa1]);
            GLD16(Wg + kn, &smem[pb ^ 1][4096 + sa0]);
            GLD16(Wg + 16 * (long)K + kn, &smem[pb ^ 1][4096 + sa1]);
        }
        const ushort_t* Ab = smem[pb];
        const ushort_t* Wb = smem[pb] + 4096;
        short8 af[4], bfr[4];
#pragma unroll
        for (int i = 0; i < 4; i++)
            af[i] = *(const short8*)&Ab[(wm * 64 + i * 16 + lr) * 32 + kg * 8];
#pragma unroll
        for (int j = 0; j < 4; j++)
            bfr[j] = *(const short8*)&Wb[(wn * 64 + j * 16 + lr) * 32 + kg * 8];
#pragma unroll
        for (int i = 0; i < 4; i++)
#pragma unroll
            for (int j = 0; j < 4; j++)
                acc[i][j] = __builtin_amdgcn_mfma_f32_16x16x32_bf16(
                    af[i], bfr[j], acc[i][j], 0, 0, 0);
    }

#pragma unroll
    for (int i = 0; i < 4; i++) {
#pragma unroll
        for (int j = 0; j < 4; j++) {
            long row = row0 + wm * 64 + i * 16 + kg * 4;
            long col = col0 + wn * 64 + j * 16 + lr;
            float bv = bias ? bias[col] : 0.f;
#pragma unroll
            for (int r = 0; r < 4; r++) {
                float x = acc[i][j][r] + bv;
                if (relu) x = fmaxf(x, 0.f);
                size_t idx = (row + r) * (size_t)Cout + col;
                if (Ch)      Ch[idx] = (_Float16)x;
                else if (Cb) Cb[idx] = f2bf(x);
                else         C[idx] = x;
            }
        }
    }
}

// ---------------------------------------------------------------------------
// Merged launch: blocks [0,768) do the qkv GEMM (8192x512->1536, f16 out),
// blocks [768,1792) do the kv GEMM (16384x512->1024 with rot/transpose
// epilogue). kv depends only on membf (ready after cvt), so running it
// concurrently with qkv saves a launch gap and fills both kernels' tails.
// Barriers are block-uniform (branch at block granularity).
// ---------------------------------------------------------------------------
__global__ __launch_bounds__(256)
void gemm_qkv_kv(const ushort_t* __restrict__ A, const ushort_t* __restrict__ Wq,
                 const float* __restrict__ bq, _Float16* __restrict__ qkvh,
                 const ushort_t* __restrict__ Mem, const ushort_t* __restrict__ Wkv,
                 const float* __restrict__ bkv,
                 const float* __restrict__ sn, const float* __restrict__ cs,
                 _Float16* __restrict__ Krot, _Float16* __restrict__ Vth) {
    __shared__ __align__(16) ushort_t smem[2][8192];
    const int tid = threadIdx.x;
    const int lane = tid & 63;
    const int wid = tid >> 6;
    const int lr = lane & 15;
    const int kg = lane >> 4;
    const int sr = lane >> 2;
    const int skq = lane & 3;
    const int K = 512;

    if (blockIdx.x < 768) {
        // ---------------- qkv path: tile 128x128 of 8192x1536 ----------------
        int colb, rowb;
        xcd_swz_p(blockIdx.x, 12, 8, colb, rowb);
        const long row0 = (long)rowb * 128;
        const long col0 = (long)colb * 128;
        const int wm = wid >> 1, wn = wid & 1;
        const ushort_t* Ag = A + (row0 + wid * 32 + sr) * (long)K + skq * 8;
        const ushort_t* Wg = Wq + (col0 + wid * 32 + sr) * (long)K + skq * 8;
        const int sa0 = (wid * 32) * 32, sa1 = (wid * 32 + 16) * 32;

        f32x4 acc[4][4] = {};
        GLD16(Ag, &smem[0][sa0]);
        GLD16(Ag + 16 * (long)K, &smem[0][sa1]);
        GLD16(Wg, &smem[0][4096 + sa0]);
        GLD16(Wg + 16 * (long)K, &smem[0][4096 + sa1]);

        int pb = 0;
        for (int k0 = 0; k0 < K; k0 += 32, pb ^= 1) {
            __syncthreads();
            int kn = k0 + 32;
            if (kn < K) {
                GLD16(Ag + kn, &smem[pb ^ 1][sa0]);
                GLD16(Ag + 16 * (long)K + kn, &smem[pb ^ 1][sa1]);
                GLD16(Wg + kn, &smem[pb ^ 1][4096 + sa0]);
                GLD16(Wg + 16 * (long)K + kn, &smem[pb ^ 1][4096 + sa1]);
            }
            const ushort_t* Ab = smem[pb];
            const ushort_t* Wb = smem[pb] + 4096;
            short8 af[4], bfr[4];
#pragma unroll
            for (int i = 0; i < 4; i++)
                af[i] = *(const short8*)&Ab[(wm * 64 + i * 16 + lr) * 32 + kg * 8];
#pragma unroll
            for (int j = 0; j < 4; j++)
                bfr[j] = *(const short8*)&Wb[(wn * 64 + j * 16 + lr) * 32 + kg * 8];
#pragma unroll
            for (int i = 0; i < 4; i++)
#pragma unroll
                for (int j = 0; j < 4; j++)
                    acc[i][j] = __builtin_amdgcn_mfma_f32_16x16x32_bf16(
                        af[i], bfr[j], acc[i][j], 0, 0, 0);
        }

#pragma unroll
        for (int i = 0; i < 4; i++)
#pragma unroll
            for (int j = 0; j < 4; j++) {
                long row = row0 + wm * 64 + i * 16 + kg * 4;
                long col = col0 + wn * 64 + j * 16 + lr;
                float bv = bq[col];
#pragma unroll
                for (int r = 0; r < 4; r++)
                    qkvh[(row + r) * (size_t)1536 + col] =
                        (_Float16)(acc[i][j][r] + bv);
            }
    } else {
        // ---------------- kv path: tile 128x128 of 16384x1024 ----------------
        _Float16* Cs = (_Float16*)smem;
        int colb, rowb;
        xcd_swz_p(blockIdx.x - 768, 8, 16, colb, rowb);
        const long row0 = (long)rowb * 128;
        const int h = colb;
        const long col0 = (long)h * 128;
        const int wm = wid >> 1, wn = wid & 1;
        const ushort_t* Ag = Mem + (row0 + wid * 32 + sr) * (long)K + skq * 8;
        const ushort_t* Wg = Wkv + (col0 + wid * 32 + sr) * (long)K + skq * 8;
        const int sa0 = (wid * 32) * 32, sa1 = (wid * 32 + 16) * 32;

        f32x4 acc[4][4] = {};
        GLD16(Ag, &smem[0][sa0]);
        GLD16(Ag + 16 * (long)K, &smem[0][sa1]);
        GLD16(Wg, &smem[0][4096 + sa0]);
        GLD16(Wg + 16 * (long)K, &smem[0][4096 + sa1]);

        int pb = 0;
        for (int k0 = 0; k0 < K; k0 += 32, pb ^= 1) {
            __syncthreads();
            int kn = k0 + 32;
            if (kn < K) {
                GLD16(Ag + kn, &smem[pb ^ 1][sa0]);
                GLD16(Ag + 16 * (long)K + kn, &smem[pb ^ 1][sa1]);
                GLD16(Wg + kn, &smem[pb ^ 1][4096 + sa0]);
                GLD16(Wg + 16 * (long)K + kn, &smem[pb ^ 1][4096 + sa1]);
            }
            const ushort_t* Ab = smem[pb];
            const ushort_t* Wb = smem[pb] + 4096;
            short8 af[4], bfr[4];
#pragma unroll
            for (int i = 0; i < 4; i++)
                af[i] = *(const short8*)&Ab[(wm * 64 + i * 16 + lr) * 32 + kg * 8];
#pragma unroll
            for (int j = 0; j < 4; j++)
                bfr[j] = *(const short8*)&Wb[(wn * 64 + j * 16 + lr) * 32 + kg * 8];
#pragma unroll
            for (int i = 0; i < 4; i++)
#pragma unroll
                for (int j = 0; j < 4; j++)
                    acc[i][j] = __builtin_amdgcn_mfma_f32_16x16x32_bf16(
                        af[i], bfr[j], acc[i][j], 0, 0, 0);
        }

        const int b_ = (int)(row0 >> 10);
        const int m0_ = (int)(row0 & 1023);
#pragma unroll
        for (int half = 0; half < 2; half++) {
            __syncthreads();
            if (wn == half) {
#pragma unroll
                for (int i = 0; i < 4; i++)
#pragma unroll
                    for (int j = 0; j < 4; j++) {
                        int row = wm * 64 + i * 16 + kg * 4;
                        int col = j * 16 + lr;
                        float bv = bkv[col0 + half * 64 + col];
#pragma unroll
                        for (int r = 0; r < 4; r++)
                            Cs[(row + r) * 76 + col] = (_Float16)(acc[i][j][r] + bv);
                    }
            }
            __syncthreads();
            if (half == 0) {
                for (int idx = tid; idx < 4096; idx += 256) {
                    int rr = idx >> 5, j = idx & 31;
                    size_t srow = (size_t)row0 + rr;
                    float x0 = (float)Cs[rr * 76 + 2 * j];
                    float x1 = (float)Cs[rr * 76 + 2 * j + 1];
                    float s = sn[srow * 32 + j], c = cs[srow * 32 + j];
                    Krot[srow * 512 + h * 64 + j]      = (_Float16)(x0 * c - x1 * s);
                    Krot[srow * 512 + h * 64 + 32 + j] = (_Float16)(x1 * c + x0 * s);
                }
            } else {
                for (int idx = tid; idx < 1024; idx += 256) {
                    int d = idx >> 4, c = idx & 15;
                    half8 v;
#pragma unroll
                    for (int k = 0; k < 8; k++) v[k] = Cs[(c * 8 + k) * 76 + d];
                    *(half8*)(Vth + (((size_t)(b_ * NHH + h)) * 64 + d) * MM
                              + m0_ + c * 8) = v;
                }
            }
        }
    }
}

// ---------------------------------------------------------------------------
// bf16 MFMA GEMM, tile 128x64, BK=32, 4 waves, each 32x64. Double-buffered.
// ---------------------------------------------------------------------------
__global__ __launch_bounds__(256)
void gemm_bf64(const ushort_t* __restrict__ A, const ushort_t* __restrict__ W,
               const float* __restrict__ bias, float* __restrict__ C,
               ushort_t* __restrict__ Cb, _Float16* __restrict__ Ch,
               int K, int Cout, int relu) {
    __shared__ __align__(16) ushort_t smem[2][6144];
    const int tid = threadIdx.x;
    const int lane = tid & 63;
    const int w = tid >> 6;
    int colb, rowb;
    xcd_swizzle(colb, rowb);
    const long row0 = (long)rowb * 128;
    const long col0 = (long)colb * 64;

    const int sr = lane >> 2;
    const int skq = lane & 3;
    const ushort_t* Ag = A + (row0 + w * 32 + sr) * (long)K + skq * 8;
    const ushort_t* Wg = W + (col0 + w * 16 + sr) * (long)K + skq * 8;
    const int sa0 = (w * 32) * 32, sa1 = (w * 32 + 16) * 32;
    const int sw0 = 4096 + (w * 16) * 32;

    f32x4 acc[2][4] = {};
    const int lr = lane & 15;
    const int kg = lane >> 4;

    GLD16(Ag, &smem[0][sa0]);
    GLD16(Ag + 16 * (long)K, &smem[0][sa1]);
    GLD16(Wg, &smem[0][sw0]);

    int pb = 0;
    for (int k0 = 0; k0 < K; k0 += 32, pb ^= 1) {
        __syncthreads();
        int kn = k0 + 32;
        if (kn < K) {
            GLD16(Ag + kn, &smem[pb ^ 1][sa0]);
            GLD16(Ag + 16 * (long)K + kn, &smem[pb ^ 1][sa1]);
            GLD16(Wg + kn, &smem[pb ^ 1][sw0]);
        }
        const ushort_t* Ab = smem[pb];
        const ushort_t* Wb = smem[pb] + 4096;
        short8 af[2], bfr[4];
#pragma unroll
        for (int i = 0; i < 2; i++)
            af[i] = *(const short8*)&Ab[(w * 32 + i * 16 + lr) * 32 + kg * 8];
#pragma unroll
        for (int j = 0; j < 4; j++)
            bfr[j] = *(const short8*)&Wb[(j * 16 + lr) * 32 + kg * 8];
#pragma unroll
        for (int i = 0; i < 2; i++)
#pragma unroll
            for (int j = 0; j < 4; j++)
                acc[i][j] = __builtin_amdgcn_mfma_f32_16x16x32_bf16(
                    af[i], bfr[j], acc[i][j], 0, 0, 0);
    }

#pragma unroll
    for (int i = 0; i < 2; i++) {
#pragma unroll
        for (int j = 0; j < 4; j++) {
            long row = row0 + w * 32 + i * 16 + kg * 4;
            long col = col0 + j * 16 + lr;
            float bv = bias ? bias[col] : 0.f;
#pragma unroll
            for (int r = 0; r < 4; r++) {
                float x = acc[i][j][r] + bv;
                if (relu) x = fmaxf(x, 0.f);
                size_t idx = (row + r) * (size_t)Cout + col;
                if (Ch)      Ch[idx] = (_Float16)x;
                else if (Cb) Cb[idx] = f2bf(x);
                else         C[idx] = x;
            }
        }
    }
}

// ---------------------------------------------------------------------------
// gemm_bf64_sk: split-K=2 variant for h @ w2.T (A stride lda, K-slice per z).
// ---------------------------------------------------------------------------
__global__ __launch_bounds__(256)
void gemm_bf64_sk(const ushort_t* __restrict__ A, const ushort_t* __restrict__ W,
                  int lda, int Kslice, float* __restrict__ C0,
                  float* __restrict__ C1, int Cout) {
    __shared__ __align__(16) ushort_t smem[2][6144];
    const int tid = threadIdx.x;
    const int lane = tid & 63;
    const int w = tid >> 6;
    int colb, rowb;
    xcd_swizzle(colb, rowb);
    const long row0 = (long)rowb * 128;
    const long col0 = (long)colb * 64;
    const long koff = (long)blockIdx.z * Kslice;
    float* __restrict__ C = blockIdx.z ? C1 : C0;

    const int sr = lane >> 2;
    const int skq = lane & 3;
    const ushort_t* Ag = A + (row0 + w * 32 + sr) * (long)lda + koff + skq * 8;
    const ushort_t* Wg = W + (col0 + w * 16 + sr) * (long)lda + koff + skq * 8;
    const int sa0 = (w * 32) * 32, sa1 = (w * 32 + 16) * 32;
    const int sw0 = 4096 + (w * 16) * 32;

    f32x4 acc[2][4] = {};
    const int lr = lane & 15;
    const int kg = lane >> 4;

    GLD16(Ag, &smem[0][sa0]);
    GLD16(Ag + 16 * (long)lda, &smem[0][sa1]);
    GLD16(Wg, &smem[0][sw0]);

    int pb = 0;
    for (int k0 = 0; k0 < Kslice; k0 += 32, pb ^= 1) {
        __syncthreads();
        int kn = k0 + 32;
        if (kn < Kslice) {
            GLD16(Ag + kn, &smem[pb ^ 1][sa0]);
            GLD16(Ag + 16 * (long)lda + kn, &smem[pb ^ 1][sa1]);
            GLD16(Wg + kn, &smem[pb ^ 1][sw0]);
        }
        const ushort_t* Ab = smem[pb];
        const ushort_t* Wb = smem[pb] + 4096;
        short8 af[2], bfr[4];
#pragma unroll
        for (int i = 0; i < 2; i++)
            af[i] = *(const short8*)&Ab[(w * 32 + i * 16 + lr) * 32 + kg * 8];
#pragma unroll
        for (int j = 0; j < 4; j++)
            bfr[j] = *(const short8*)&Wb[(j * 16 + lr) * 32 + kg * 8];
#pragma unroll
        for (int i = 0; i < 2; i++)
#pragma unroll
            for (int j = 0; j < 4; j++)
                acc[i][j] = __builtin_amdgcn_mfma_f32_16x16x32_bf16(
                    af[i], bfr[j], acc[i][j], 0, 0, 0);
    }

#pragma unroll
    for (int i = 0; i < 2; i++)
#pragma unroll
        for (int j = 0; j < 4; j++) {
            long row = row0 + w * 32 + i * 16 + kg * 4;
            long col = col0 + j * 16 + lr;
#pragma unroll
            for (int r = 0; r < 4; r++)
                C[(row + r) * (size_t)Cout + col] = acc[i][j][r];
        }
}

// ---------------------------------------------------------------------------
// gemm_q_rot: 128x64-tile GEMM (Cout=512, K=512), col-block = one head.
// ---------------------------------------------------------------------------
__global__ __launch_bounds__(256)
void gemm_q_rot(const ushort_t* __restrict__ A, const ushort_t* __restrict__ W,
                const float* __restrict__ bias,
                const float* __restrict__ sn, const float* __restrict__ cs,
                _Float16* __restrict__ Qrot) {
    __shared__ __align__(16) ushort_t smem[2][6144];
    _Float16* Cs = (_Float16*)smem;
    const int K = 512;
    const int tid = threadIdx.x;
    const int lane = tid & 63;
    const int w = tid >> 6;
    int colb, rowb;
    xcd_swizzle(colb, rowb);
    const long row0 = (long)rowb * 128;
    const int h = colb;
    const long col0 = (long)h * 64;

    const int sr = lane >> 2;
    const int skq = lane & 3;
    const ushort_t* Ag = A + (row0 + w * 32 + sr) * (long)K + skq * 8;
    const ushort_t* Wg = W + (col0 + w * 16 + sr) * (long)K + skq * 8;
    const int sa0 = (w * 32) * 32, sa1 = (w * 32 + 16) * 32;
    const int sw0 = 4096 + (w * 16) * 32;

    f32x4 acc[2][4] = {};
    const int lr = lane & 15;
    const int kg = lane >> 4;

    GLD16(Ag, &smem[0][sa0]);
    GLD16(Ag + 16 * (long)K, &smem[0][sa1]);
    GLD16(Wg, &smem[0][sw0]);

    int pb = 0;
    for (int k0 = 0; k0 < K; k0 += 32, pb ^= 1) {
        __syncthreads();
        int kn = k0 + 32;
        if (kn < K) {
            GLD16(Ag + kn, &smem[pb ^ 1][sa0]);
            GLD16(Ag + 16 * (long)K + kn, &smem[pb ^ 1][sa1]);
            GLD16(Wg + kn, &smem[pb ^ 1][sw0]);
        }
        const ushort_t* Ab = smem[pb];
        const ushort_t* Wb = smem[pb] + 4096;
        short8 af[2], bfr[4];
#pragma unroll
        for (int i = 0; i < 2; i++)
            af[i] = *(const short8*)&Ab[(w * 32 + i * 16 + lr) * 32 + kg * 8];
#pragma unroll
        for (int j = 0; j < 4; j++)
            bfr[j] = *(const short8*)&Wb[(j * 16 + lr) * 32 + kg * 8];
#pragma unroll
        for (int i = 0; i < 2; i++)
#pragma unroll
            for (int j = 0; j < 4; j++)
                acc[i][j] = __builtin_amdgcn_mfma_f32_16x16x32_bf16(
                    af[i], bfr[j], acc[i][j], 0, 0, 0);
    }

    __syncthreads();
#pragma unroll
    for (int i = 0; i < 2; i++)
#pragma unroll
        for (int j = 0; j < 4; j++) {
            int row = w * 32 + i * 16 + kg * 4;
            int col = j * 16 + lr;
            float bv = bias[col0 + col];
#pragma unroll
            for (int r = 0; r < 4; r++)
                Cs[(row + r) * 76 + col] = (_Float16)(acc[i][j][r] + bv);
        }
    __syncthreads();
    for (int idx = tid; idx < 4096; idx += 256) {
        int rr = idx >> 5, j = idx & 31;
        size_t srow = (size_t)row0 + rr;
        float x0 = (float)Cs[rr * 76 + 2 * j], x1 = (float)Cs[rr * 76 + 2 * j + 1];
        float s = sn[srow * 32 + j], c = cs[srow * 32 + j];
        Qrot[srow * 512 + h * 64 + j]      = (_Float16)(x0 * c - x1 * s);
        Qrot[srow * 512 + h * 64 + 32 + j] = (_Float16)(x1 * c + x0 * s);
    }
}

// ---------------------------------------------------------------------------
// One-shot fp32->bf16 convert of tgt, mem, and all 7 weight mats.
// ---------------------------------------------------------------------------
__global__ __launch_bounds__(256)
void cvt_all(const float* __restrict__ tgt, const float* __restrict__ mem,
             const float* __restrict__ w0, const float* __restrict__ w1,
             const float* __restrict__ w2, const float* __restrict__ w3,
             const float* __restrict__ w4, const float* __restrict__ w5,
             const float* __restrict__ w6,
             ushort_t* __restrict__ Abf, ushort_t* __restrict__ membf,
             ushort_t* __restrict__ Wbf) {
    int blk = blockIdx.x;
    const float* src;
    ushort_t* dst;
    size_t off;
    if (blk < 4096)       { src = tgt; dst = Abf;   off = (size_t)blk * 1024; }
    else if (blk < 12288) { src = mem; dst = membf; off = (size_t)(blk - 4096) * 1024; }
    else {
        int wb = blk - 12288;
        dst = Wbf + (size_t)wb * 1024;
        if (wb < 768)       { src = w0; off = (size_t)wb * 1024; }
        else if (wb < 1024) { src = w1; off = (size_t)(wb - 768) * 1024; }
        else if (wb < 1280) { src = w2; off = (size_t)(wb - 1024) * 1024; }
        else if (wb < 1792) { src = w3; off = (size_t)(wb - 1280) * 1024; }
        else if (wb < 2048) { src = w4; off = (size_t)(wb - 1792) * 1024; }
        else if (wb < 3072) { src = w5; off = (size_t)(wb - 2048) * 1024; }
        else                { src = w6; off = (size_t)(wb - 3072) * 1024; }
        float4 v = *(const float4*)(src + off + threadIdx.x * 4);
        ushort4 o;
        o.x = f2bf(v.x); o.y = f2bf(v.y); o.z = f2bf(v.z); o.w = f2bf(v.w);
        *(ushort4*)(dst + threadIdx.x * 4) = o;
        return;
    }
    float4 v = *(const float4*)(src + off + threadIdx.x * 4);
    ushort4 o;
    o.x = f2bf(v.x); o.y = f2bf(v.y); o.z = f2bf(v.z); o.w = f2bf(v.w);
    *(ushort4*)(dst + off + threadIdx.x * 4) = o;
}

// ---------------------------------------------------------------------------
// prep_vt: transpose 64-wide V slice per head (self-attention path).
// ---------------------------------------------------------------------------
__global__ __launch_bounds__(256)
void prep_vt(const _Float16* __restrict__ src, int L, int stride,
             int hmul, int hadd, _Float16* __restrict__ Vt) {
    const int b = blockIdx.z, h = blockIdx.y, m0 = blockIdx.x * 64;
    const int tid = threadIdx.x;
    __shared__ _Float16 vt[64][72];
    for (int idx = tid; idx < 512; idx += 256) {
        int m = idx >> 3, c = idx & 7;
        half8 v = *(const half8*)(src + ((size_t)(b * L + m0 + m)) * stride
                                  + h * hmul + hadd + c * 8);
#pragma unroll
        for (int k = 0; k < 8; k++) vt[c * 8 + k][m] = v[k];
    }
    __syncthreads();
    for (int idx = tid; idx < 512; idx += 256) {
        int d = idx >> 3, c = idx & 7;
        *(half8*)(Vt + (((size_t)(b * NHH + h)) * 64 + d) * L + m0 + c * 8)
            = *(const half8*)&vt[d][c * 8];
    }
}

// ---------------------------------------------------------------------------
// Flash MFMA attention v11: 4-wave / 64-q blocks, grid 1024.
// vs v10 (8-wave/128-q, grid 512): same 16 waves/CU, but LDS = 40KB exactly
// -> 4 blocks/CU = 4 INDEPENDENT barrier domains per CU (was 2). When one
// block drains at its barrier, three others issue -> the per-tile serial
// chain (QK -> softmax -> P roundtrip -> PV) hides behind other blocks.
// Self-attn: qb in [0,8), balanced via packed-nibble perm [0,3,5,6,7,4,2,1]
// so co-resident sets {q,q+2,q+4,q+6} each sum to 18 tile-units (packed in
// a u32 constant -> no runtime-indexed array, no scratch).
// Keeps v10's: defer-max on partial max, per-lane partial lrun, cvt_pkrtz,
// exp2-form softmax, setprio, XOR chunk swizzle, dbuf + depth-2 prefetch.
// ---------------------------------------------------------------------------
__global__ __launch_bounds__(256, 4)
void attn11(const _Float16* __restrict__ Q, int qstride, int qmul, int qadd,
            const _Float16* __restrict__ K, int kstride, int kmul, int kadd,
            const _Float16* __restrict__ Vt, int LV, int Lrows,
            ushort_t* __restrict__ out, int kvlen, int causal) {
    const int g = blockIdx.x;
    const int bh = (g & 7) * 16 + ((g >> 3) & 15);
    const int qraw = g >> 7;                        // 0..7
    const int qb = causal ? ((0x12476530u >> (qraw << 2)) & 7) : qraw;
    const int b = bh >> 3, h = bh & 7;
    const int n0 = qb * 64;
    const int tid = threadIdx.x, lane = tid & 63, w = tid >> 6;  // w 0..3
    const int quad = lane >> 4, l16 = lane & 15;
    const int qw = n0 + w * 16;                     // 16 q rows per wave

    __shared__ _Float16 Ks[2][64 * 64];
    __shared__ _Float16 Vs[2][64 * 64];
    __shared__ _Float16 Ps[4][16 * 64];
    _Float16* Pw = Ps[w];

    half8 bq[2];
#pragma unroll
    for (int c = 0; c < 2; c++)
        bq[c] = *(const half8*)(Q + ((size_t)(b * NN + qw + l16)) * qstride
                                + h * qmul + qadd + c * 32 + quad * 8);

    f32x4 acc[4] = {};
    float mrun = -3e38f, lrun = 0.f;                // lrun = per-lane PARTIAL

    const int srow = tid >> 3;                      // 0..31 (256 threads)
    const int scol = tid & 7;                       // chunk index 0..7
    const int ssw = (scol ^ (srow & 7)) * 8;        // swizzle; (srow+32)&7==srow&7

    const int limit = causal ? (n0 + 64) : kvlen;
    const int nt = limit >> 6;

    const size_t kbase = ((size_t)(b * Lrows)) * kstride + h * kmul + kadd;
    const size_t vbase = (((size_t)(b * NHH + h)) * 64 + srow) * (size_t)LV;

    // prologue: tile 0 -> buf0 (2 rows/thread); issue tile-1 loads into regs
    half8 kr0, kr1, vr0, vr1;
    {
        size_t kb = kbase + (size_t)srow * kstride + scol * 8;
        kr0 = *(const half8*)(K + kb);
        kr1 = *(const half8*)(K + kb + (size_t)32 * kstride);
        vr0 = *(const half8*)(Vt + vbase + scol * 8);
        vr1 = *(const half8*)(Vt + vbase + (size_t)32 * LV + scol * 8);
    }
    *(half8*)&Ks[0][srow * 64 + ssw] = kr0;
    *(half8*)&Ks[0][(srow + 32) * 64 + ssw] = kr1;
    *(half8*)&Vs[0][srow * 64 + ssw] = vr0;
    *(half8*)&Vs[0][(srow + 32) * 64 + ssw] = vr1;
    if (nt > 1) {
        size_t kb = kbase + (size_t)(64 + srow) * kstride + scol * 8;
        kr0 = *(const half8*)(K + kb);
        kr1 = *(const half8*)(K + kb + (size_t)32 * kstride);
        vr0 = *(const half8*)(Vt + vbase + 64 + scol * 8);
        vr1 = *(const half8*)(Vt + vbase + (size_t)32 * LV + 64 + scol * 8);
    }

    const float SC = 0.125f * 1.44269504f;          // scale * log2(e)
    const int fsw = l16 & 7;                        // frag-read row swizzle
    int pb = 0;
    for (int t = 0; t < nt; t++, pb ^= 1) {
        const int key0 = t * 64;
        __syncthreads();
        if (t + 1 < nt) {
            *(half8*)&Ks[pb ^ 1][srow * 64 + ssw] = kr0;
            *(half8*)&Ks[pb ^ 1][(srow + 32) * 64 + ssw] = kr1;
            *(half8*)&Vs[pb ^ 1][srow * 64 + ssw] = vr0;
            *(half8*)&Vs[pb ^ 1][(srow + 32) * 64 + ssw] = vr1;
            if (t + 2 < nt) {
                size_t kb = kbase + (size_t)((t + 2) * 64 + srow) * kstride + scol * 8;
                kr0 = *(const half8*)(K + kb);
                kr1 = *(const half8*)(K + kb + (size_t)32 * kstride);
                vr0 = *(const half8*)(Vt + vbase + (t + 2) * 64 + scol * 8);
                vr1 = *(const half8*)(Vt + vbase + (size_t)32 * LV
                                      + (t + 2) * 64 + scol * 8);
            }
        }

        const _Float16* Kb = Ks[pb];
        const _Float16* Vb = Vs[pb];
        f32x4 st[4];
        __builtin_amdgcn_s_setprio(1);
#pragma unroll
        for (int kt = 0; kt < 4; kt++) {
            const int rk = kt * 16 + l16;
            half8 ak0 = *(const half8*)&Kb[rk * 64 + ((quad ^ fsw) * 8)];
            half8 ak1 = *(const half8*)&Kb[rk * 64 + (((quad + 4) ^ fsw) * 8)];
            f32x4 z = {};
            z = __builtin_amdgcn_mfma_f32_16x16x32_f16(ak0, bq[0], z, 0, 0, 0);
            z = __builtin_amdgcn_mfma_f32_16x16x32_f16(ak1, bq[1], z, 0, 0, 0);
            st[kt] = z;
        }
        __builtin_amdgcn_s_setprio(0);

        if (causal && key0 + 64 > qw) {
            const int qabs = qw + l16;
#pragma unroll
            for (int kt = 0; kt < 4; kt++)
#pragma unroll
                for (int r = 0; r < 4; r++)
                    if (key0 + kt * 16 + quad * 4 + r > qabs)
                        st[kt][r] = -3e38f;
        }

        float plm = -3e38f;
#pragma unroll
        for (int kt = 0; kt < 4; kt++)
            plm = fmaxf(plm, fmaxf(fmaxf(st[kt][0], st[kt][1]),
                                   fmaxf(st[kt][2], st[kt][3])));

        const int keep = __all(plm - mrun <= 64.f);
        if (!keep) {
            float lm = fmaxf(plm, __shfl_xor(plm, 16));
            lm = fmaxf(lm, __shfl_xor(lm, 32));
            float mnew = fmaxf(mrun, lm);
            float corr = exp2f((mrun - mnew) * SC);
            mrun = mnew;
            lrun *= corr;
            float cb0 = __shfl(corr, (lane & 48) | (quad * 4 + 0));
            float cb1 = __shfl(corr, (lane & 48) | (quad * 4 + 1));
            float cb2 = __shfl(corr, (lane & 48) | (quad * 4 + 2));
            float cb3 = __shfl(corr, (lane & 48) | (quad * 4 + 3));
#pragma unroll
            for (int dt = 0; dt < 4; dt++) {
                acc[dt][0] *= cb0; acc[dt][1] *= cb1;
                acc[dt][2] *= cb2; acc[dt][3] *= cb3;
            }
        }
        const float mb = mrun * SC;
#pragma unroll
        for (int kt = 0; kt < 4; kt++) {
            float p0 = exp2f(__builtin_fmaf(st[kt][0], SC, -mb));
            float p1 = exp2f(__builtin_fmaf(st[kt][1], SC, -mb));
            float p2 = exp2f(__builtin_fmaf(st[kt][2], SC, -mb));
            float p3 = exp2f(__builtin_fmaf(st[kt][3], SC, -mb));
            lrun += (p0 + p1) + (p2 + p3);
            fp16x2 lo = __builtin_amdgcn_cvt_pkrtz(p0, p1);
            fp16x2 hi = __builtin_amdgcn_cvt_pkrtz(p2, p3);
            union { unsigned u[2]; half4 h; } pk;
            pk.u[0] = __builtin_bit_cast(unsigned, lo);
            pk.u[1] = __builtin_bit_cast(unsigned, hi);
            int jc = 2 * kt + (quad >> 1);
            *(half4*)&Pw[l16 * 64 + ((jc ^ fsw) * 8) + (quad & 1) * 4] = pk.h;
        }
        half8 ap[2];
#pragma unroll
        for (int c = 0; c < 2; c++)
            ap[c] = *(const half8*)&Pw[l16 * 64 + (((c * 4 + quad) ^ fsw) * 8)];
        __builtin_amdgcn_s_setprio(1);
#pragma unroll
        for (int dt = 0; dt < 4; dt++) {
            const int rv = dt * 16 + l16;
            half8 bv0 = *(const half8*)&Vb[rv * 64 + ((quad ^ fsw) * 8)];
            half8 bv1 = *(const half8*)&Vb[rv * 64 + (((quad + 4) ^ fsw) * 8)];
            acc[dt] = __builtin_amdgcn_mfma_f32_16x16x32_f16(ap[0], bv0, acc[dt], 0, 0, 0);
            acc[dt] = __builtin_amdgcn_mfma_f32_16x16x32_f16(ap[1], bv1, acc[dt], 0, 0, 0);
        }
        __builtin_amdgcn_s_setprio(0);
    }

    lrun += __shfl_xor(lrun, 16);
    lrun += __shfl_xor(lrun, 32);
    float invq = 1.f / lrun;
    float iv0 = __shfl(invq, (lane & 48) | (quad * 4 + 0));
    float iv1 = __shfl(invq, (lane & 48) | (quad * 4 + 1));
    float iv2 = __shfl(invq, (lane & 48) | (quad * 4 + 2));
    float iv3 = __shfl(invq, (lane & 48) | (quad * 4 + 3));
#pragma unroll
    for (int dt = 0; dt < 4; dt++) {
        size_t base = ((size_t)(b * NN + qw + quad * 4)) * 512
                      + h * 64 + dt * 16 + l16;
        out[base]           = f2bf(acc[dt][0] * iv0);
        out[base + 512]     = f2bf(acc[dt][1] * iv1);
        out[base + 1024]    = f2bf(acc[dt][2] * iv2);
        out[base + 1536]    = f2bf(acc[dt][3] * iv3);
    }
}

// ---------------------------------------------------------------------------
// out = LayerNorm(u + (u2?) + res)*g + beta; optional bf16 copy.
// ---------------------------------------------------------------------------
__global__ __launch_bounds__(256)
void ln_residual(const float* __restrict__ u, const float* __restrict__ u2,
                 const float* __restrict__ res,
                 const float* __restrict__ g, const float* __restrict__ be,
                 float* __restrict__ out, ushort_t* __restrict__ outbf) {
    const int row = blockIdx.x, t = threadIdx.x;
    const float* rp = res + (size_t)row * HIDD;
    const float* up = u + (size_t)row * HIDD;
    float z0 = rp[t] + up[t];
    float z1 = rp[t + 256] + up[t + 256];
    if (u2) {
        const float* up2 = u2 + (size_t)row * HIDD;
        z0 += up2[t];
        z1 += up2[t + 256];
    }
    float sm = z0 + z1, s2 = z0 * z0 + z1 * z1;
#pragma unroll
    for (int off = 1; off < 64; off <<= 1) {
        sm += __shfl_xor(sm, off, 64);
        s2 += __shfl_xor(s2, off, 64);
    }
    __shared__ float ps[4], ps2[4];
    int w = t >> 6;
    if ((t & 63) == 0) { ps[w] = sm; ps2[w] = s2; }
    __syncthreads();
    sm = ps[0] + ps[1] + ps[2] + ps[3];
    s2 = ps2[0] + ps2[1] + ps2[2] + ps2[3];
    float mu = sm * (1.f / 512.f);
    float var = s2 * (1.f / 512.f) - mu * mu;
    float rstd = rsqrtf(var + 1e-5f);
    float y0 = (z0 - mu) * rstd * g[t] + be[t];
    float y1 = (z1 - mu) * rstd * g[t + 256] + be[t + 256];
    out[(size_t)row * HIDD + t]       = y0;
    out[(size_t)row * HIDD + t + 256] = y1;
    if (outbf) {
        outbf[(size_t)row * HIDD + t]       = f2bf(y0);
        outbf[(size_t)row * HIDD + t + 256] = f2bf(y1);
    }
}

// ---------------------------------------------------------------------------
extern "C" void kernel_launch(void* const* d_in, const int* in_sizes, int n_in,
                              void* d_out, int out_size, void* d_ws, size_t ws_size,
                              hipStream_t stream) {
    const float* tgt      = (const float*)d_in[0];
    const float* mem      = (const float*)d_in[1];
    const float* pep_sin  = (const float*)d_in[2];
    const float* pep_cos  = (const float*)d_in[3];
    const float* pk_sin   = (const float*)d_in[4];
    const float* pk_cos   = (const float*)d_in[5];
    const float* mmha_w   = (const float*)d_in[8];
    const float* mmha_b   = (const float*)d_in[9];
    const float* mmha_ow  = (const float*)d_in[10];
    const float* mmha_ob  = (const float*)d_in[11];
    const float* mmha_g   = (const float*)d_in[12];
    const float* mmha_be  = (const float*)d_in[13];
    const float* mha_qw   = (const float*)d_in[14];
    const float* mha_qb   = (const float*)d_in[15];
    const float* mha_kvw  = (const float*)d_in[16];
    const float* mha_kvb  = (const float*)d_in[17];
    const float* mha_ow   = (const float*)d_in[18];
    const float* mha_ob   = (const float*)d_in[19];
    const float* mha_g    = (const float*)d_in[20];
    const float* mha_be   = (const float*)d_in[21];
    const float* ffn_w1   = (const float*)d_in[22];
    const float* ffn_w2   = (const float*)d_in[23];
    const float* ffn_g    = (const float*)d_in[24];
    const float* ffn_be   = (const float*)d_in[25];

    float* ws = (float*)d_ws;
    float* utmp  = ws;                        //  4,194,304 f32
    float* tgt12 = ws + 4194304;              //  4,194,304 f32
    _Float16* hp = (_Float16*)(ws + 8388608); // half pool (offsets in halves)
    _Float16* qkvh  = hp;                     // 12,582,912 (B*N*1536)
    _Float16* Qrot  = hp + 12582912;          //  4,194,304
    _Float16* Vth   = hp + 16777216;          //  8,388,608 (cross V, [b,h,64,MM])
    _Float16* Krot  = hp + 25165824;          //  8,388,608
    ushort_t* membf = (ushort_t*)(hp + 33554432); // 8,388,608 bf16
    ushort_t* Abf   = (ushort_t*)(hp + 41943040); // 4,194,304 bf16
    ushort_t* Wbf   = (ushort_t*)(hp + 46137344); // 4,194,304 bf16 weights
    ushort_t* w_mmha = Wbf;                   //   786,432
    ushort_t* w_mmow = Wbf + 786432;          //   262,144
    ushort_t* w_qw   = Wbf + 1048576;         //   262,144
    ushort_t* w_kvw  = Wbf + 1310720;         //   524,288
    ushort_t* w_mow  = Wbf + 1835008;         //   262,144
    ushort_t* w_f1   = Wbf + 2097152;         // 1,048,576
    ushort_t* w_f2   = Wbf + 3145728;         // 1,048,576
    _Float16* Vth_self = hp + 50331648;       //  4,194,304 (self V, [b,h,64,NN])
    ushort_t* hbf = (ushort_t*)qkvh;          // ffn hidden bf16 spans qkvh+Qrot
    float* utmp2 = (float*)Krot;              // dead after cross-attn; split-K slice 1
    float* out = (float*)d_out;
    (void)in_sizes; (void)n_in; (void)out_size; (void)ws_size;

    // 0. all fp32->bf16 converts in one launch
    cvt_all<<<16384, 256, 0, stream>>>(tgt, mem, mmha_w, mmha_ow, mha_qw,
                                       mha_kvw, mha_ow, ffn_w1, ffn_w2,
                                       Abf, membf, Wbf);
    // 1. merged qkv GEMM (768 blocks) + kv GEMM w/ rot+transpose (1024 blocks)
    gemm_qkv_kv<<<1792, 256, 0, stream>>>(Abf, w_mmha, mmha_b, qkvh,
                                          membf, w_kvw, mha_kvb,
                                          pk_sin, pk_cos, Krot, Vth);
    // 2. self-attention (causal), v11 (4-wave/64-q, grid 1024)
    prep_vt<<<dim3(8, NHH, BB), 256, 0, stream>>>(qkvh, NN, 1536, 192, 128, Vth_self);
    attn11<<<1024, 256, 0, stream>>>(qkvh, 1536, 192, 0, qkvh, 1536, 192, 64,
                                     Vth_self, NN, NN, Abf, 0, 1);
    // 3. tgt1 = LN(x @ ow.T + ob + tgt)
    gemm_bf64<<<dim3(8, 64), 256, 0, stream>>>(Abf, w_mmow, mmha_ob, utmp, nullptr, nullptr, 512, 512, 0);
    ln_residual<<<8192, 256, 0, stream>>>(utmp, nullptr, tgt, mmha_g, mmha_be, tgt12, Abf);
    // 4. Qrot = rot(tgt1 @ qw.T + qb)
    gemm_q_rot<<<dim3(8, 64), 256, 0, stream>>>(Abf, w_qw, mha_qb, pep_sin, pep_cos, Qrot);
    // 5. cross-attention (960 valid keys), v11
    attn11<<<1024, 256, 0, stream>>>(Qrot, 512, 64, 0, Krot, 512, 64, 0,
                                     Vth, MM, MM, Abf, MM - 64, 0);
    // 6. tgt2 = LN(x2 @ ow.T + ob + tgt1)
    gemm_bf64<<<dim3(8, 64), 256, 0, stream>>>(Abf, w_mow, mha_ob, utmp, nullptr, nullptr, 512, 512, 0);
    ln_residual<<<8192, 256, 0, stream>>>(utmp, nullptr, tgt12, mha_g, mha_be, tgt12, Abf);
    // 7. h = relu(tgt2 @ w1.T)     (8192x512x2048, bf16 out)
    gemm_bf<<<dim3(16, 64), 256, 0, stream>>>(Abf, w_f1, nullptr, nullptr, hbf, nullptr, 512, 2048, 1);
    // 8. h2 = h @ w2.T  (8192x2048x512) split-K=2, 1024 blocks
    gemm_bf64_sk<<<dim3(8, 64, 2), 256, 0, stream>>>(hbf, w_f2, 2048, 1024, utmp, utmp2, 512);
    // 9. out = LN(tgt2 + h2a + h2b)
    ln_residual<<<8192, 256, 0, stream>>>(utmp, utmp2, tgt12, ffn_g, ffn_be, out, nullptr);
}